// Round 1
// baseline (1860.671 us; speedup 1.0000x reference)
//
#include <hip/hip_runtime.h>
#include <cmath>

// Problem constants (from reference): N=50000 nodes, E=800000 edges, B=64 graphs,
// H=2 heads, D=128, FIN=128, L=2 lstm layers.

__device__ __forceinline__ float sigmoidf_(float x){ return 1.f/(1.f+expf(-x)); }

// ---------------- CSR build (by dst) ----------------
__global__ void k_hist(const int* __restrict__ dst, int* __restrict__ deg, int E){
  int e = blockIdx.x*blockDim.x + threadIdx.x;
  if (e < E) atomicAdd(&deg[dst[e]], 1);
}

// single-block exclusive scan over n ints, writes out[0..n] (out[n] = total)
__global__ void k_exscan(const int* __restrict__ in, int* __restrict__ out, int n){
  __shared__ int wsum[4];
  __shared__ int s_carry;
  int tid = threadIdx.x, lane = tid & 63, wid = tid >> 6;
  if (tid == 0) s_carry = 0;
  __syncthreads();
  for (int base = 0; base < n; base += 256){
    int i = base + tid;
    int orig = (i < n) ? in[i] : 0;
    int v = orig;
    for (int o = 1; o < 64; o <<= 1){ int t = __shfl_up(v, o); if (lane >= o) v += t; }
    if (lane == 63) wsum[wid] = v;
    __syncthreads();
    int wpre = 0;
    for (int w = 0; w < wid; w++) wpre += wsum[w];
    int carry = s_carry;
    if (i < n) out[i] = carry + wpre + v - orig;
    __syncthreads();
    if (tid == 255) s_carry = carry + wpre + v;
  }
  __syncthreads();
  if (tid == 0) out[n] = s_carry;
}

__global__ void k_scatter(const int* __restrict__ dst, const int* __restrict__ offs,
                          int* __restrict__ cnt, int* __restrict__ eidx, int E){
  int e = blockIdx.x*blockDim.x + threadIdx.x;
  if (e < E){ int d = dst[e]; int p = atomicAdd(&cnt[d], 1); eidx[offs[d] + p] = e; }
}

// graph boundaries from sorted node_graph: gstart[b] = first node of graph b, gstart[B]=N
__global__ void k_graph_bounds(const int* __restrict__ ng, int* __restrict__ gstart, int n, int nb){
  int i = blockIdx.x*blockDim.x + threadIdx.x;
  if (i >= n) return;
  int g = ng[i];
  int gp = (i == 0) ? -1 : ng[i-1];
  for (int b = gp+1; b <= g; b++) gstart[b] = i;
  if (i == n-1) for (int b = g+1; b <= nb; b++) gstart[b] = n;
}

// ---------------- f32 GEMM: Y[M,256] = X[M,128] @ W[128,256] ----------------
// 64x64 tile, 256 threads, 4x4 microtile, BK=64 (two k-tiles).
__global__ __launch_bounds__(256) void k_gemm(const float* __restrict__ X, const float* __restrict__ Wm,
                                              float* __restrict__ Y, int M){
  __shared__ float As[64][68];  // [m][k], pad 68 (16B-aligned rows, spread banks)
  __shared__ float Bs[64][64];  // [k][n]
  int m0 = blockIdx.x * 64;
  int n0 = blockIdx.y * 64;
  int tid = threadIdx.x;
  int tr = tid >> 4, tc = tid & 15;
  float acc[4][4] = {};
  for (int kb = 0; kb < 2; kb++){
    #pragma unroll
    for (int i = 0; i < 4; i++){
      int f = (tid + i*256) * 4;          // 0..4095 over 64x64 tile
      int r = f >> 6, c = f & 63;
      int gm = m0 + r;
      float4 v = {0,0,0,0};
      if (gm < M) v = *(const float4*)(X + (size_t)gm*128 + kb*64 + c);
      *(float4*)&As[r][c] = v;
    }
    #pragma unroll
    for (int i = 0; i < 4; i++){
      int f = (tid + i*256) * 4;
      int r = f >> 6, c = f & 63;
      *(float4*)&Bs[r][c] = *(const float4*)(Wm + (size_t)(kb*64 + r)*256 + n0 + c);
    }
    __syncthreads();
    #pragma unroll
    for (int k = 0; k < 64; k += 4){
      float4 a[4], b[4];
      #pragma unroll
      for (int j = 0; j < 4; j++) a[j] = *(const float4*)&As[tr*4 + j][k];
      #pragma unroll
      for (int j = 0; j < 4; j++) b[j] = *(const float4*)&Bs[k + j][tc*4];
      #pragma unroll
      for (int kk = 0; kk < 4; kk++){
        #pragma unroll
        for (int r = 0; r < 4; r++){
          float av = ((const float*)&a[r])[kk];
          float4 bv = b[kk];
          acc[r][0] += av*bv.x; acc[r][1] += av*bv.y; acc[r][2] += av*bv.z; acc[r][3] += av*bv.w;
        }
      }
    }
    __syncthreads();
  }
  #pragma unroll
  for (int r = 0; r < 4; r++){
    int gm = m0 + tr*4 + r;
    if (gm < M){
      float4 v = { acc[r][0], acc[r][1], acc[r][2], acc[r][3] };
      *(float4*)(Y + (size_t)gm*256 + n0 + tc*4) = v;
    }
  }
}

// ---------------- per-node attention scores el/er: wave per node ----------------
__global__ __launch_bounds__(256) void k_node_scores(const float* __restrict__ hpair,
    const float* __restrict__ al, const float* __restrict__ ar,
    float* __restrict__ el, float* __restrict__ er, int Nn){
  int n = blockIdx.x*4 + (threadIdx.x >> 6);
  if (n >= Nn) return;
  int lane = threadIdx.x & 63;
  float4 h = *(const float4*)(hpair + (size_t)n*256 + lane*4);  // flat [2][128]
  float4 a = *(const float4*)(al + lane*4);
  float4 r = *(const float4*)(ar + lane*4);
  float pe = h.x*a.x + h.y*a.y + h.z*a.z + h.w*a.w;
  float pr = h.x*r.x + h.y*r.y + h.z*r.z + h.w*r.w;
  for (int k = 1; k < 32; k <<= 1){ pe += __shfl_xor(pe, k); pr += __shfl_xor(pr, k); }
  if ((lane & 31) == 0){
    int head = lane >> 5;
    el[(size_t)n*2 + head] = pe;
    er[(size_t)n*2 + head] = pr;
  }
}

// ---------------- per-edge leaky-relu scores ----------------
__global__ void k_edge_scores(const float* __restrict__ el, const float* __restrict__ er,
    const int* __restrict__ src, const int* __restrict__ dst, float* __restrict__ escore, int E){
  int e = blockIdx.x*blockDim.x + threadIdx.x;
  if (e >= E) return;
  int s = src[e], d = dst[e];
  float2 l = *(const float2*)(el + (size_t)s*2);
  float2 r = *(const float2*)(er + (size_t)d*2);
  float v0 = l.x + r.x, v1 = l.y + r.y;
  v0 = (v0 > 0.f) ? v0 : 0.2f*v0;
  v1 = (v1 > 0.f) ? v1 : 0.2f*v1;
  float2 o = { v0, v1 };
  *(float2*)(escore + (size_t)e*2) = o;
}

// ---------------- per-node softmax + aggregation + bias + relu + head-mean ----------------
// wave per node; lanes 0..31 = head0 dims, lanes 32..63 = head1 dims (4 dims each).
__global__ __launch_bounds__(256) void k_aggregate(const float* __restrict__ hpair,
    const float* __restrict__ escore, const int* __restrict__ src,
    const int* __restrict__ offs, const int* __restrict__ eidx,
    const float* __restrict__ bias, float* __restrict__ out, int Nn){
  int n = blockIdx.x*4 + (threadIdx.x >> 6);
  if (n >= Nn) return;
  int lane = threadIdx.x & 63;
  int e0 = offs[n], e1 = offs[n+1];
  float m0 = -3.4e38f, m1 = -3.4e38f;
  for (int i = e0 + lane; i < e1; i += 64){
    int e = eidx[i];
    float2 sc = *(const float2*)(escore + (size_t)e*2);
    m0 = fmaxf(m0, sc.x); m1 = fmaxf(m1, sc.y);
  }
  for (int k = 1; k < 64; k <<= 1){ m0 = fmaxf(m0, __shfl_xor(m0, k)); m1 = fmaxf(m1, __shfl_xor(m1, k)); }
  float s0 = 0.f, s1 = 0.f;
  for (int i = e0 + lane; i < e1; i += 64){
    int e = eidx[i];
    float2 sc = *(const float2*)(escore + (size_t)e*2);
    s0 += expf(sc.x - m0); s1 += expf(sc.y - m1);
  }
  for (int k = 1; k < 64; k <<= 1){ s0 += __shfl_xor(s0, k); s1 += __shfl_xor(s1, k); }
  int head = lane >> 5;
  float m = head ? m1 : m0;
  float inv = head ? (s1 > 0.f ? 1.f/s1 : 0.f) : (s0 > 0.f ? 1.f/s0 : 0.f);
  float ax = 0.f, ay = 0.f, az = 0.f, aw = 0.f;
  for (int i = e0; i < e1; i++){
    int e = eidx[i];
    float w = expf(escore[(size_t)e*2 + head] - m) * inv;
    float4 hv = *(const float4*)(hpair + (size_t)src[e]*256 + lane*4);
    ax += w*hv.x; ay += w*hv.y; az += w*hv.z; aw += w*hv.w;
  }
  float ox = __shfl_xor(ax, 32), oy = __shfl_xor(ay, 32), oz = __shfl_xor(az, 32), ow = __shfl_xor(aw, 32);
  if (lane < 32){
    int d = lane*4;
    float4 b0 = *(const float4*)(bias + d);
    float4 b1 = *(const float4*)(bias + 128 + d);
    float4 rr;
    rr.x = 0.5f*(fmaxf(ax + b0.x, 0.f) + fmaxf(ox + b1.x, 0.f));
    rr.y = 0.5f*(fmaxf(ay + b0.y, 0.f) + fmaxf(oy + b1.y, 0.f));
    rr.z = 0.5f*(fmaxf(az + b0.z, 0.f) + fmaxf(oz + b1.z, 0.f));
    rr.w = 0.5f*(fmaxf(aw + b0.w, 0.f) + fmaxf(ow + b1.w, 0.f));
    *(float4*)(out + (size_t)n*128 + d) = rr;
  }
}

// ---------------- pool gate: gate[n] = dot(x[n], gw) + gb ----------------
__global__ __launch_bounds__(256) void k_gate(const float* __restrict__ x, const float* __restrict__ gw,
    const float* __restrict__ gb, float* __restrict__ gate, int Nn){
  int n = blockIdx.x*4 + (threadIdx.x >> 6);
  if (n >= Nn) return;
  int lane = threadIdx.x & 63;
  float2 xv = *(const float2*)(x + (size_t)n*128 + lane*2);
  float2 gv = *(const float2*)(gw + lane*2);
  float p = xv.x*gv.x + xv.y*gv.y;
  for (int k = 1; k < 64; k <<= 1) p += __shfl_xor(p, k);
  if (lane == 0) gate[n] = p + gb[0];
}

// ---------------- global attention pool: block per graph ----------------
__global__ __launch_bounds__(256) void k_pool(const float* __restrict__ x, const float* __restrict__ gate,
    const int* __restrict__ gstart, float* __restrict__ hg){
  int b = blockIdx.x;
  int n0 = gstart[b], n1 = gstart[b+1];
  int tid = threadIdx.x, lane = tid & 63, wid = tid >> 6;
  __shared__ float red[4];
  float m = -3.4e38f;
  for (int n = n0 + tid; n < n1; n += 256) m = fmaxf(m, gate[n]);
  for (int k = 1; k < 64; k <<= 1) m = fmaxf(m, __shfl_xor(m, k));
  if (lane == 0) red[wid] = m;
  __syncthreads();
  m = fmaxf(fmaxf(red[0], red[1]), fmaxf(red[2], red[3]));
  __syncthreads();
  float s = 0.f;
  for (int n = n0 + tid; n < n1; n += 256) s += expf(gate[n] - m);
  for (int k = 1; k < 64; k <<= 1) s += __shfl_xor(s, k);
  if (lane == 0) red[wid] = s;
  __syncthreads();
  s = red[0] + red[1] + red[2] + red[3];
  float inv = (s > 0.f) ? 1.f/s : 0.f;
  if (tid < 128){
    float acc = 0.f;
    for (int n = n0; n < n1; n++) acc += expf(gate[n] - m) * x[(size_t)n*128 + tid];
    hg[(size_t)b*128 + tid] = acc * inv;
  }
}

// ---------------- LSTM step: block per batch row, 512 threads (one per gate unit) ----------------
__global__ __launch_bounds__(512) void k_lstm(const float* __restrict__ xin,
    const float* __restrict__ Wih, const float* __restrict__ Whh,
    const float* __restrict__ bih, const float* __restrict__ bhh,
    float* __restrict__ hstate, float* __restrict__ cstate, float* __restrict__ seqOut){
  int b = blockIdx.x;
  int j = threadIdx.x;
  __shared__ float xh[256];
  __shared__ float gates[512];
  if (j < 128) xh[j] = xin[(size_t)b*128 + j];
  else if (j < 256) xh[j] = hstate[(size_t)b*128 + (j - 128)];
  __syncthreads();
  float g = bih[j] + bhh[j];
  const float4* wi4 = (const float4*)(Wih + (size_t)j*128);
  const float4* wh4 = (const float4*)(Whh + (size_t)j*128);
  #pragma unroll 8
  for (int k = 0; k < 32; k++){
    float4 wi = wi4[k], wh = wh4[k];
    g += xh[4*k+0]*wi.x + xh[4*k+1]*wi.y + xh[4*k+2]*wi.z + xh[4*k+3]*wi.w;
    g += xh[128+4*k+0]*wh.x + xh[128+4*k+1]*wh.y + xh[128+4*k+2]*wh.z + xh[128+4*k+3]*wh.w;
  }
  gates[j] = g;
  __syncthreads();
  if (j < 128){
    float gi = sigmoidf_(gates[j]);
    float gf = sigmoidf_(gates[128 + j]);
    float gg = tanhf(gates[256 + j]);
    float go = sigmoidf_(gates[384 + j]);
    float c = gf * cstate[(size_t)b*128 + j] + gi * gg;
    float h = go * tanhf(c);
    cstate[(size_t)b*128 + j] = c;
    hstate[(size_t)b*128 + j] = h;
    seqOut[(size_t)b*128 + j] = h;
  }
}

// ---------------- final: sigmoid(h @ cw + cb) ----------------
__global__ void k_final(const float* __restrict__ h, const float* __restrict__ cw,
                        const float* __restrict__ cb, float* __restrict__ out){
  int b = threadIdx.x;
  float s = 0.f;
  for (int k = 0; k < 128; k++) s += h[(size_t)b*128 + k] * cw[k];
  out[b] = sigmoidf_(s + cb[0]);
}

extern "C" void kernel_launch(void* const* d_in, const int* in_sizes, int n_in,
                              void* d_out, int out_size, void* d_ws, size_t ws_size,
                              hipStream_t stream){
  const float* nfeats = (const float*)d_in[0];
  const int*   src    = (const int*)d_in[1];
  const int*   dst    = (const int*)d_in[2];
  const int*   ng     = (const int*)d_in[3];
  const float* Wm[3]  = { (const float*)d_in[4],  (const float*)d_in[8],  (const float*)d_in[12] };
  const float* al[3]  = { (const float*)d_in[5],  (const float*)d_in[9],  (const float*)d_in[13] };
  const float* ar[3]  = { (const float*)d_in[6],  (const float*)d_in[10], (const float*)d_in[14] };
  const float* bb[3]  = { (const float*)d_in[7],  (const float*)d_in[11], (const float*)d_in[15] };
  const float* gw[4]  = { (const float*)d_in[16], (const float*)d_in[18], (const float*)d_in[20], (const float*)d_in[22] };
  const float* gb[4]  = { (const float*)d_in[17], (const float*)d_in[19], (const float*)d_in[21], (const float*)d_in[23] };
  const float* Wih = (const float*)d_in[24];
  const float* Whh = (const float*)d_in[25];
  const float* bih = (const float*)d_in[26];
  const float* bhh = (const float*)d_in[27];
  const float* cw  = (const float*)d_in[28];
  const float* cb  = (const float*)d_in[29];

  const int N = in_sizes[3];      // 50000
  const int E = in_sizes[1];      // 800000
  const int B = out_size;         // 64

  char* p = (char*)d_ws;
  auto alloc = [&](size_t bytes) -> void* {
    void* q = (void*)p;
    p += (bytes + 255) & ~(size_t)255;
    return q;
  };
  float* hpair  = (float*)alloc((size_t)N*256*4);
  float* xbuf   = (float*)alloc((size_t)N*128*4);
  float* el     = (float*)alloc((size_t)N*2*4);
  float* er     = (float*)alloc((size_t)N*2*4);
  float* escore = (float*)alloc((size_t)E*2*4);
  float* gate   = (float*)alloc((size_t)N*4);
  int*   deg    = (int*)alloc((size_t)N*4);
  int*   offs   = (int*)alloc((size_t)(N+1)*4);
  int*   cnt    = (int*)alloc((size_t)N*4);
  int*   eidx   = (int*)alloc((size_t)E*4);
  int*   gstart = (int*)alloc((size_t)(B+1)*4);
  float* seqA   = (float*)alloc((size_t)4*B*128*4);
  float* seqB   = (float*)alloc((size_t)4*B*128*4);
  float* hstate = (float*)alloc((size_t)B*128*4);
  float* cstate = (float*)alloc((size_t)B*128*4);

  auto cdiv = [](int a, int b){ return (a + b - 1) / b; };

  // CSR by dst + graph bounds
  hipMemsetAsync(deg, 0, (size_t)N*4, stream);
  hipMemsetAsync(cnt, 0, (size_t)N*4, stream);
  k_hist<<<cdiv(E,256), 256, 0, stream>>>(dst, deg, E);
  k_exscan<<<1, 256, 0, stream>>>(deg, offs, N);
  k_scatter<<<cdiv(E,256), 256, 0, stream>>>(dst, offs, cnt, eidx, E);
  k_graph_bounds<<<cdiv(N,256), 256, 0, stream>>>(ng, gstart, N, B);

  // pool 0 on raw features
  k_gate<<<cdiv(N,4), 256, 0, stream>>>(nfeats, gw[0], gb[0], gate, N);
  k_pool<<<B, 256, 0, stream>>>(nfeats, gate, gstart, seqA + 0*(size_t)B*128);

  const float* x = nfeats;
  for (int layer = 0; layer < 3; layer++){
    dim3 ggrid(cdiv(N,64), 4);
    k_gemm<<<ggrid, 256, 0, stream>>>(x, Wm[layer], hpair, N);
    k_node_scores<<<cdiv(N,4), 256, 0, stream>>>(hpair, al[layer], ar[layer], el, er, N);
    k_edge_scores<<<cdiv(E,256), 256, 0, stream>>>(el, er, src, dst, escore, E);
    k_aggregate<<<cdiv(N,4), 256, 0, stream>>>(hpair, escore, src, offs, eidx, bb[layer], xbuf, N);
    x = xbuf;
    k_gate<<<cdiv(N,4), 256, 0, stream>>>(x, gw[layer+1], gb[layer+1], gate, N);
    k_pool<<<B, 256, 0, stream>>>(x, gate, gstart, seqA + (size_t)(layer+1)*B*128);
  }

  // LSTM: layer 0 reads seqA -> seqB; layer 1 reads seqB -> seqA (seq out unused except hstate)
  for (int l = 0; l < 2; l++){
    hipMemsetAsync(hstate, 0, (size_t)B*128*4, stream);
    hipMemsetAsync(cstate, 0, (size_t)B*128*4, stream);
    const float* sin = (l == 0) ? seqA : seqB;
    float* sout = (l == 0) ? seqB : seqA;
    for (int t = 0; t < 4; t++){
      k_lstm<<<B, 512, 0, stream>>>(sin + (size_t)t*B*128,
                                    Wih + (size_t)l*512*128, Whh + (size_t)l*512*128,
                                    bih + (size_t)l*512, bhh + (size_t)l*512,
                                    hstate, cstate, sout + (size_t)t*B*128);
    }
  }
  k_final<<<1, B, 0, stream>>>(hstate, cw, cb, (float*)d_out);
}

// Round 2
// 1148.528 us; speedup vs baseline: 1.6200x; 1.6200x over previous
//
#include <hip/hip_runtime.h>
#include <cmath>

// Problem constants (from reference): N=50000 nodes, E=800000 edges, B=64 graphs,
// H=2 heads, D=128, FIN=128, L=2 lstm layers.

__device__ __forceinline__ float sigmoidf_(float x){ return 1.f/(1.f+expf(-x)); }

// ---------------- CSR build (by dst) ----------------
__global__ void k_hist(const int* __restrict__ dst, int* __restrict__ deg, int E){
  int e = blockIdx.x*blockDim.x + threadIdx.x;
  if (e < E) atomicAdd(&deg[dst[e]], 1);
}

// single-block exclusive scan over n ints, writes out[0..n] (out[n] = total)
__global__ void k_exscan(const int* __restrict__ in, int* __restrict__ out, int n){
  __shared__ int wsum[4];
  __shared__ int s_carry;
  int tid = threadIdx.x, lane = tid & 63, wid = tid >> 6;
  if (tid == 0) s_carry = 0;
  __syncthreads();
  for (int base = 0; base < n; base += 256){
    int i = base + tid;
    int orig = (i < n) ? in[i] : 0;
    int v = orig;
    for (int o = 1; o < 64; o <<= 1){ int t = __shfl_up(v, o); if (lane >= o) v += t; }
    if (lane == 63) wsum[wid] = v;
    __syncthreads();
    int wpre = 0;
    for (int w = 0; w < wid; w++) wpre += wsum[w];
    int carry = s_carry;
    if (i < n) out[i] = carry + wpre + v - orig;
    __syncthreads();
    if (tid == 255) s_carry = carry + wpre + v;
  }
  __syncthreads();
  if (tid == 0) out[n] = s_carry;
}

__global__ void k_scatter(const int* __restrict__ dst, const int* __restrict__ offs,
                          int* __restrict__ cnt, int* __restrict__ eidx, int E){
  int e = blockIdx.x*blockDim.x + threadIdx.x;
  if (e < E){ int d = dst[e]; int p = atomicAdd(&cnt[d], 1); eidx[offs[d] + p] = e; }
}

// graph boundaries from sorted node_graph: gstart[b] = first node of graph b, gstart[B]=N
__global__ void k_graph_bounds(const int* __restrict__ ng, int* __restrict__ gstart, int n, int nb){
  int i = blockIdx.x*blockDim.x + threadIdx.x;
  if (i >= n) return;
  int g = ng[i];
  int gp = (i == 0) ? -1 : ng[i-1];
  for (int b = gp+1; b <= g; b++) gstart[b] = i;
  if (i == n-1) for (int b = g+1; b <= nb; b++) gstart[b] = n;
}

// ---------------- f32 GEMM: Y[M,256] = X[M,128] @ W[128,256] ----------------
// 64x64 tile, 256 threads, 4x4 microtile, BK=64 (two k-tiles).
__global__ __launch_bounds__(256) void k_gemm(const float* __restrict__ X, const float* __restrict__ Wm,
                                              float* __restrict__ Y, int M){
  __shared__ float As[64][68];  // [m][k], pad 68 (16B-aligned rows, spread banks)
  __shared__ float Bs[64][64];  // [k][n]
  int m0 = blockIdx.x * 64;
  int n0 = blockIdx.y * 64;
  int tid = threadIdx.x;
  int tr = tid >> 4, tc = tid & 15;
  float acc[4][4] = {};
  for (int kb = 0; kb < 2; kb++){
    #pragma unroll
    for (int i = 0; i < 4; i++){
      int f = (tid + i*256) * 4;          // 0..4095 over 64x64 tile
      int r = f >> 6, c = f & 63;
      int gm = m0 + r;
      float4 v = {0,0,0,0};
      if (gm < M) v = *(const float4*)(X + (size_t)gm*128 + kb*64 + c);
      *(float4*)&As[r][c] = v;
    }
    #pragma unroll
    for (int i = 0; i < 4; i++){
      int f = (tid + i*256) * 4;
      int r = f >> 6, c = f & 63;
      *(float4*)&Bs[r][c] = *(const float4*)(Wm + (size_t)(kb*64 + r)*256 + n0 + c);
    }
    __syncthreads();
    #pragma unroll
    for (int k = 0; k < 64; k += 4){
      float4 a[4], b[4];
      #pragma unroll
      for (int j = 0; j < 4; j++) a[j] = *(const float4*)&As[tr*4 + j][k];
      #pragma unroll
      for (int j = 0; j < 4; j++) b[j] = *(const float4*)&Bs[k + j][tc*4];
      #pragma unroll
      for (int kk = 0; kk < 4; kk++){
        #pragma unroll
        for (int r = 0; r < 4; r++){
          float av = ((const float*)&a[r])[kk];
          float4 bv = b[kk];
          acc[r][0] += av*bv.x; acc[r][1] += av*bv.y; acc[r][2] += av*bv.z; acc[r][3] += av*bv.w;
        }
      }
    }
    __syncthreads();
  }
  #pragma unroll
  for (int r = 0; r < 4; r++){
    int gm = m0 + tr*4 + r;
    if (gm < M){
      float4 v = { acc[r][0], acc[r][1], acc[r][2], acc[r][3] };
      *(float4*)(Y + (size_t)gm*256 + n0 + tc*4) = v;
    }
  }
}

// ---------------- per-node attention scores el/er: wave per node ----------------
__global__ __launch_bounds__(256) void k_node_scores(const float* __restrict__ hpair,
    const float* __restrict__ al, const float* __restrict__ ar,
    float* __restrict__ el, float* __restrict__ er, int Nn){
  int n = blockIdx.x*4 + (threadIdx.x >> 6);
  if (n >= Nn) return;
  int lane = threadIdx.x & 63;
  float4 h = *(const float4*)(hpair + (size_t)n*256 + lane*4);  // flat [2][128]
  float4 a = *(const float4*)(al + lane*4);
  float4 r = *(const float4*)(ar + lane*4);
  float pe = h.x*a.x + h.y*a.y + h.z*a.z + h.w*a.w;
  float pr = h.x*r.x + h.y*r.y + h.z*r.z + h.w*r.w;
  for (int k = 1; k < 32; k <<= 1){ pe += __shfl_xor(pe, k); pr += __shfl_xor(pr, k); }
  if ((lane & 31) == 0){
    int head = lane >> 5;
    el[(size_t)n*2 + head] = pe;
    er[(size_t)n*2 + head] = pr;
  }
}

// ---------------- per-edge leaky-relu scores ----------------
__global__ void k_edge_scores(const float* __restrict__ el, const float* __restrict__ er,
    const int* __restrict__ src, const int* __restrict__ dst, float* __restrict__ escore, int E){
  int e = blockIdx.x*blockDim.x + threadIdx.x;
  if (e >= E) return;
  int s = src[e], d = dst[e];
  float2 l = *(const float2*)(el + (size_t)s*2);
  float2 r = *(const float2*)(er + (size_t)d*2);
  float v0 = l.x + r.x, v1 = l.y + r.y;
  v0 = (v0 > 0.f) ? v0 : 0.2f*v0;
  v1 = (v1 > 0.f) ? v1 : 0.2f*v1;
  float2 o = { v0, v1 };
  *(float2*)(escore + (size_t)e*2) = o;
}

// ---------------- per-node softmax + aggregation + bias + relu + head-mean ----------------
// wave per node; lanes 0..31 = head0 dims, lanes 32..63 = head1 dims (4 dims each).
__global__ __launch_bounds__(256) void k_aggregate(const float* __restrict__ hpair,
    const float* __restrict__ escore, const int* __restrict__ src,
    const int* __restrict__ offs, const int* __restrict__ eidx,
    const float* __restrict__ bias, float* __restrict__ out, int Nn){
  int n = blockIdx.x*4 + (threadIdx.x >> 6);
  if (n >= Nn) return;
  int lane = threadIdx.x & 63;
  int e0 = offs[n], e1 = offs[n+1];
  float m0 = -3.4e38f, m1 = -3.4e38f;
  for (int i = e0 + lane; i < e1; i += 64){
    int e = eidx[i];
    float2 sc = *(const float2*)(escore + (size_t)e*2);
    m0 = fmaxf(m0, sc.x); m1 = fmaxf(m1, sc.y);
  }
  for (int k = 1; k < 64; k <<= 1){ m0 = fmaxf(m0, __shfl_xor(m0, k)); m1 = fmaxf(m1, __shfl_xor(m1, k)); }
  float s0 = 0.f, s1 = 0.f;
  for (int i = e0 + lane; i < e1; i += 64){
    int e = eidx[i];
    float2 sc = *(const float2*)(escore + (size_t)e*2);
    s0 += expf(sc.x - m0); s1 += expf(sc.y - m1);
  }
  for (int k = 1; k < 64; k <<= 1){ s0 += __shfl_xor(s0, k); s1 += __shfl_xor(s1, k); }
  int head = lane >> 5;
  float m = head ? m1 : m0;
  float inv = head ? (s1 > 0.f ? 1.f/s1 : 0.f) : (s0 > 0.f ? 1.f/s0 : 0.f);
  float ax = 0.f, ay = 0.f, az = 0.f, aw = 0.f;
  for (int i = e0; i < e1; i++){
    int e = eidx[i];
    float w = expf(escore[(size_t)e*2 + head] - m) * inv;
    float4 hv = *(const float4*)(hpair + (size_t)src[e]*256 + lane*4);
    ax += w*hv.x; ay += w*hv.y; az += w*hv.z; aw += w*hv.w;
  }
  float ox = __shfl_xor(ax, 32), oy = __shfl_xor(ay, 32), oz = __shfl_xor(az, 32), ow = __shfl_xor(aw, 32);
  if (lane < 32){
    int d = lane*4;
    float4 b0 = *(const float4*)(bias + d);
    float4 b1 = *(const float4*)(bias + 128 + d);
    float4 rr;
    rr.x = 0.5f*(fmaxf(ax + b0.x, 0.f) + fmaxf(ox + b1.x, 0.f));
    rr.y = 0.5f*(fmaxf(ay + b0.y, 0.f) + fmaxf(oy + b1.y, 0.f));
    rr.z = 0.5f*(fmaxf(az + b0.z, 0.f) + fmaxf(oz + b1.z, 0.f));
    rr.w = 0.5f*(fmaxf(aw + b0.w, 0.f) + fmaxf(ow + b1.w, 0.f));
    *(float4*)(out + (size_t)n*128 + d) = rr;
  }
}

// ---------------- pool gate: gate[n] = dot(x[n], gw) + gb ----------------
__global__ __launch_bounds__(256) void k_gate(const float* __restrict__ x, const float* __restrict__ gw,
    const float* __restrict__ gb, float* __restrict__ gate, int Nn){
  int n = blockIdx.x*4 + (threadIdx.x >> 6);
  if (n >= Nn) return;
  int lane = threadIdx.x & 63;
  float2 xv = *(const float2*)(x + (size_t)n*128 + lane*2);
  float2 gv = *(const float2*)(gw + lane*2);
  float p = xv.x*gv.x + xv.y*gv.y;
  for (int k = 1; k < 64; k <<= 1) p += __shfl_xor(p, k);
  if (lane == 0) gate[n] = p + gb[0];
}

// ---------------- pool stats: block per graph -> pm[b], psinv[b] ----------------
__global__ __launch_bounds__(256) void k_pool_stats(const float* __restrict__ gate,
    const int* __restrict__ gstart, float* __restrict__ pm, float* __restrict__ psinv){
  int b = blockIdx.x;
  int n0 = gstart[b], n1 = gstart[b+1];
  int tid = threadIdx.x, lane = tid & 63, wid = tid >> 6;
  __shared__ float red[4];
  float m = -3.4e38f;
  for (int n = n0 + tid; n < n1; n += 256) m = fmaxf(m, gate[n]);
  for (int k = 1; k < 64; k <<= 1) m = fmaxf(m, __shfl_xor(m, k));
  if (lane == 0) red[wid] = m;
  __syncthreads();
  m = fmaxf(fmaxf(red[0], red[1]), fmaxf(red[2], red[3]));
  __syncthreads();
  float s = 0.f;
  for (int n = n0 + tid; n < n1; n += 256) s += expf(gate[n] - m);
  for (int k = 1; k < 64; k <<= 1) s += __shfl_xor(s, k);
  if (lane == 0) red[wid] = s;
  __syncthreads();
  if (tid == 0){
    s = red[0] + red[1] + red[2] + red[3];
    pm[b] = m;
    psinv[b] = (s > 0.f) ? 1.f/s : 0.f;
  }
}

// ---------------- pool partial: block (b,p) accumulates weighted rows ----------------
#define POOL_P 32
__global__ __launch_bounds__(128) void k_pool_partial(const float* __restrict__ x,
    const float* __restrict__ gate, const int* __restrict__ gstart,
    const float* __restrict__ pm, const float* __restrict__ psinv,
    float* __restrict__ partials){
  int b = blockIdx.x;
  int p = blockIdx.y;
  int n0 = gstart[b], n1 = gstart[b+1];
  int tid = threadIdx.x;
  float m = pm[b], inv = psinv[b];
  float acc = 0.f;
  for (int n = n0 + p; n < n1; n += POOL_P){
    float w = expf(gate[n] - m) * inv;
    acc += w * x[(size_t)n*128 + tid];
  }
  partials[((size_t)b*POOL_P + p)*128 + tid] = acc;
}

// ---------------- pool reduce: sum partials -> hg[b][128] ----------------
__global__ __launch_bounds__(128) void k_pool_reduce(const float* __restrict__ partials,
    float* __restrict__ hg){
  int b = blockIdx.x;
  int tid = threadIdx.x;
  float s = 0.f;
  #pragma unroll
  for (int p = 0; p < POOL_P; p++) s += partials[((size_t)b*POOL_P + p)*128 + tid];
  hg[(size_t)b*128 + tid] = s;
}

// ---------------- LSTM step: block per batch row, 512 threads (one per gate unit) ----------------
__global__ __launch_bounds__(512) void k_lstm(const float* __restrict__ xin,
    const float* __restrict__ Wih, const float* __restrict__ Whh,
    const float* __restrict__ bih, const float* __restrict__ bhh,
    float* __restrict__ hstate, float* __restrict__ cstate, float* __restrict__ seqOut){
  int b = blockIdx.x;
  int j = threadIdx.x;
  __shared__ float xh[256];
  __shared__ float gates[512];
  if (j < 128) xh[j] = xin[(size_t)b*128 + j];
  else if (j < 256) xh[j] = hstate[(size_t)b*128 + (j - 128)];
  __syncthreads();
  float g = bih[j] + bhh[j];
  const float4* wi4 = (const float4*)(Wih + (size_t)j*128);
  const float4* wh4 = (const float4*)(Whh + (size_t)j*128);
  #pragma unroll 8
  for (int k = 0; k < 32; k++){
    float4 wi = wi4[k], wh = wh4[k];
    g += xh[4*k+0]*wi.x + xh[4*k+1]*wi.y + xh[4*k+2]*wi.z + xh[4*k+3]*wi.w;
    g += xh[128+4*k+0]*wh.x + xh[128+4*k+1]*wh.y + xh[128+4*k+2]*wh.z + xh[128+4*k+3]*wh.w;
  }
  gates[j] = g;
  __syncthreads();
  if (j < 128){
    float gi = sigmoidf_(gates[j]);
    float gf = sigmoidf_(gates[128 + j]);
    float gg = tanhf(gates[256 + j]);
    float go = sigmoidf_(gates[384 + j]);
    float c = gf * cstate[(size_t)b*128 + j] + gi * gg;
    float h = go * tanhf(c);
    cstate[(size_t)b*128 + j] = c;
    hstate[(size_t)b*128 + j] = h;
    seqOut[(size_t)b*128 + j] = h;
  }
}

// ---------------- final: sigmoid(h @ cw + cb) ----------------
__global__ void k_final(const float* __restrict__ h, const float* __restrict__ cw,
                        const float* __restrict__ cb, float* __restrict__ out){
  int b = threadIdx.x;
  float s = 0.f;
  for (int k = 0; k < 128; k++) s += h[(size_t)b*128 + k] * cw[k];
  out[b] = sigmoidf_(s + cb[0]);
}

extern "C" void kernel_launch(void* const* d_in, const int* in_sizes, int n_in,
                              void* d_out, int out_size, void* d_ws, size_t ws_size,
                              hipStream_t stream){
  const float* nfeats = (const float*)d_in[0];
  const int*   src    = (const int*)d_in[1];
  const int*   dst    = (const int*)d_in[2];
  const int*   ng     = (const int*)d_in[3];
  const float* Wm[3]  = { (const float*)d_in[4],  (const float*)d_in[8],  (const float*)d_in[12] };
  const float* al[3]  = { (const float*)d_in[5],  (const float*)d_in[9],  (const float*)d_in[13] };
  const float* ar[3]  = { (const float*)d_in[6],  (const float*)d_in[10], (const float*)d_in[14] };
  const float* bb[3]  = { (const float*)d_in[7],  (const float*)d_in[11], (const float*)d_in[15] };
  const float* gw[4]  = { (const float*)d_in[16], (const float*)d_in[18], (const float*)d_in[20], (const float*)d_in[22] };
  const float* gb[4]  = { (const float*)d_in[17], (const float*)d_in[19], (const float*)d_in[21], (const float*)d_in[23] };
  const float* Wih = (const float*)d_in[24];
  const float* Whh = (const float*)d_in[25];
  const float* bih = (const float*)d_in[26];
  const float* bhh = (const float*)d_in[27];
  const float* cw  = (const float*)d_in[28];
  const float* cb  = (const float*)d_in[29];

  const int N = in_sizes[3];      // 50000
  const int E = in_sizes[1];      // 800000
  const int B = out_size;         // 64

  char* p = (char*)d_ws;
  auto alloc = [&](size_t bytes) -> void* {
    void* q = (void*)p;
    p += (bytes + 255) & ~(size_t)255;
    return q;
  };
  float* hpair  = (float*)alloc((size_t)N*256*4);
  float* xbuf   = (float*)alloc((size_t)N*128*4);
  float* el     = (float*)alloc((size_t)N*2*4);
  float* er     = (float*)alloc((size_t)N*2*4);
  float* escore = (float*)alloc((size_t)E*2*4);
  float* gate   = (float*)alloc((size_t)N*4);
  int*   deg    = (int*)alloc((size_t)N*4);
  int*   offs   = (int*)alloc((size_t)(N+1)*4);
  int*   cnt    = (int*)alloc((size_t)N*4);
  int*   eidx   = (int*)alloc((size_t)E*4);
  int*   gstart = (int*)alloc((size_t)(B+1)*4);
  float* seqA   = (float*)alloc((size_t)4*B*128*4);
  float* seqB   = (float*)alloc((size_t)4*B*128*4);
  float* hstate = (float*)alloc((size_t)B*128*4);
  float* cstate = (float*)alloc((size_t)B*128*4);
  float* pm     = (float*)alloc((size_t)B*4);
  float* psinv  = (float*)alloc((size_t)B*4);
  float* partials = (float*)alloc((size_t)B*POOL_P*128*4);

  auto cdiv = [](int a, int b){ return (a + b - 1) / b; };

  // CSR by dst + graph bounds
  hipMemsetAsync(deg, 0, (size_t)N*4, stream);
  hipMemsetAsync(cnt, 0, (size_t)N*4, stream);
  k_hist<<<cdiv(E,256), 256, 0, stream>>>(dst, deg, E);
  k_exscan<<<1, 256, 0, stream>>>(deg, offs, N);
  k_scatter<<<cdiv(E,256), 256, 0, stream>>>(dst, offs, cnt, eidx, E);
  k_graph_bounds<<<cdiv(N,256), 256, 0, stream>>>(ng, gstart, N, B);

  auto pool = [&](const float* xv, const float* gwv, const float* gbv, float* hgv){
    k_gate<<<cdiv(N,4), 256, 0, stream>>>(xv, gwv, gbv, gate, N);
    k_pool_stats<<<B, 256, 0, stream>>>(gate, gstart, pm, psinv);
    dim3 pg(B, POOL_P);
    k_pool_partial<<<pg, 128, 0, stream>>>(xv, gate, gstart, pm, psinv, partials);
    k_pool_reduce<<<B, 128, 0, stream>>>(partials, hgv);
  };

  // pool 0 on raw features
  pool(nfeats, gw[0], gb[0], seqA + 0*(size_t)B*128);

  const float* x = nfeats;
  for (int layer = 0; layer < 3; layer++){
    dim3 ggrid(cdiv(N,64), 4);
    k_gemm<<<ggrid, 256, 0, stream>>>(x, Wm[layer], hpair, N);
    k_node_scores<<<cdiv(N,4), 256, 0, stream>>>(hpair, al[layer], ar[layer], el, er, N);
    k_edge_scores<<<cdiv(E,256), 256, 0, stream>>>(el, er, src, dst, escore, E);
    k_aggregate<<<cdiv(N,4), 256, 0, stream>>>(hpair, escore, src, offs, eidx, bb[layer], xbuf, N);
    x = xbuf;
    pool(x, gw[layer+1], gb[layer+1], seqA + (size_t)(layer+1)*B*128);
  }

  // LSTM: layer 0 reads seqA -> seqB; layer 1 reads seqB -> seqA (seq out unused except hstate)
  for (int l = 0; l < 2; l++){
    hipMemsetAsync(hstate, 0, (size_t)B*128*4, stream);
    hipMemsetAsync(cstate, 0, (size_t)B*128*4, stream);
    const float* sin = (l == 0) ? seqA : seqB;
    float* sout = (l == 0) ? seqB : seqA;
    for (int t = 0; t < 4; t++){
      k_lstm<<<B, 512, 0, stream>>>(sin + (size_t)t*B*128,
                                    Wih + (size_t)l*512*128, Whh + (size_t)l*512*128,
                                    bih + (size_t)l*512, bhh + (size_t)l*512,
                                    hstate, cstate, sout + (size_t)t*B*128);
    }
  }
  k_final<<<1, B, 0, stream>>>(hstate, cw, cb, (float*)d_out);
}

// Round 3
// 946.763 us; speedup vs baseline: 1.9653x; 1.2131x over previous
//
#include <hip/hip_runtime.h>
#include <cmath>

// N=50000 nodes, E=800000 edges, B=64 graphs, H=2 heads, D=128, FIN=128, L=2.

__device__ __forceinline__ float sigmoidf_(float x){ return 1.f/(1.f+expf(-x)); }

__device__ __forceinline__ unsigned f2bf_rne(float f){
  unsigned u = __float_as_uint(f);
  return (u + 0x7fffu + ((u >> 16) & 1u)) >> 16;   // round-nearest-even bf16
}
__device__ __forceinline__ float bf_lo(unsigned u){ return __uint_as_float(u << 16); }
__device__ __forceinline__ float bf_hi(unsigned u){ return __uint_as_float(u & 0xffff0000u); }

// ---------------- CSR build (by dst) ----------------
__global__ void k_hist(const int* __restrict__ dst, int* __restrict__ deg, int E){
  int e = blockIdx.x*blockDim.x + threadIdx.x;
  if (e < E) atomicAdd(&deg[dst[e]], 1);
}

__global__ void k_exscan(const int* __restrict__ in, int* __restrict__ out, int n){
  __shared__ int wsum[4];
  __shared__ int s_carry;
  int tid = threadIdx.x, lane = tid & 63, wid = tid >> 6;
  if (tid == 0) s_carry = 0;
  __syncthreads();
  for (int base = 0; base < n; base += 256){
    int i = base + tid;
    int orig = (i < n) ? in[i] : 0;
    int v = orig;
    for (int o = 1; o < 64; o <<= 1){ int t = __shfl_up(v, o); if (lane >= o) v += t; }
    if (lane == 63) wsum[wid] = v;
    __syncthreads();
    int wpre = 0;
    for (int w = 0; w < wid; w++) wpre += wsum[w];
    int carry = s_carry;
    if (i < n) out[i] = carry + wpre + v - orig;
    __syncthreads();
    if (tid == 255) s_carry = carry + wpre + v;
  }
  __syncthreads();
  if (tid == 0) out[n] = s_carry;
}

__global__ void k_scatter(const int* __restrict__ dst, const int* __restrict__ offs,
                          int* __restrict__ cnt, int* __restrict__ eidx, int E){
  int e = blockIdx.x*blockDim.x + threadIdx.x;
  if (e < E){ int d = dst[e]; int p = atomicAdd(&cnt[d], 1); eidx[offs[d] + p] = e; }
}

__global__ void k_graph_bounds(const int* __restrict__ ng, int* __restrict__ gstart, int n, int nb){
  int i = blockIdx.x*blockDim.x + threadIdx.x;
  if (i >= n) return;
  int g = ng[i];
  int gp = (i == 0) ? -1 : ng[i-1];
  for (int b = gp+1; b <= g; b++) gstart[b] = i;
  if (i == n-1) for (int b = g+1; b <= nb; b++) gstart[b] = n;
}

// ---------------- f32 GEMM: Y[M,256] = X[M,128] @ W[128,256], + bf16 copy ----------------
__global__ __launch_bounds__(256) void k_gemm(const float* __restrict__ X, const float* __restrict__ Wm,
                                              float* __restrict__ Y, ushort* __restrict__ Yh, int M){
  __shared__ float As[64][68];
  __shared__ float Bs[64][64];
  int m0 = blockIdx.x * 64;
  int n0 = blockIdx.y * 64;
  int tid = threadIdx.x;
  int tr = tid >> 4, tc = tid & 15;
  float acc[4][4] = {};
  for (int kb = 0; kb < 2; kb++){
    #pragma unroll
    for (int i = 0; i < 4; i++){
      int f = (tid + i*256) * 4;
      int r = f >> 6, c = f & 63;
      int gm = m0 + r;
      float4 v = {0,0,0,0};
      if (gm < M) v = *(const float4*)(X + (size_t)gm*128 + kb*64 + c);
      *(float4*)&As[r][c] = v;
    }
    #pragma unroll
    for (int i = 0; i < 4; i++){
      int f = (tid + i*256) * 4;
      int r = f >> 6, c = f & 63;
      *(float4*)&Bs[r][c] = *(const float4*)(Wm + (size_t)(kb*64 + r)*256 + n0 + c);
    }
    __syncthreads();
    #pragma unroll
    for (int k = 0; k < 64; k += 4){
      float4 a[4], b[4];
      #pragma unroll
      for (int j = 0; j < 4; j++) a[j] = *(const float4*)&As[tr*4 + j][k];
      #pragma unroll
      for (int j = 0; j < 4; j++) b[j] = *(const float4*)&Bs[k + j][tc*4];
      #pragma unroll
      for (int kk = 0; kk < 4; kk++){
        #pragma unroll
        for (int r = 0; r < 4; r++){
          float av = ((const float*)&a[r])[kk];
          float4 bv = b[kk];
          acc[r][0] += av*bv.x; acc[r][1] += av*bv.y; acc[r][2] += av*bv.z; acc[r][3] += av*bv.w;
        }
      }
    }
    __syncthreads();
  }
  #pragma unroll
  for (int r = 0; r < 4; r++){
    int gm = m0 + tr*4 + r;
    if (gm < M){
      float4 v = { acc[r][0], acc[r][1], acc[r][2], acc[r][3] };
      *(float4*)(Y + (size_t)gm*256 + n0 + tc*4) = v;
      ushort4 hv = { (ushort)f2bf_rne(v.x), (ushort)f2bf_rne(v.y),
                     (ushort)f2bf_rne(v.z), (ushort)f2bf_rne(v.w) };
      *(ushort4*)(Yh + (size_t)gm*256 + n0 + tc*4) = hv;
    }
  }
}

// ---------------- per-node attention scores el/er ----------------
__global__ __launch_bounds__(256) void k_node_scores(const float* __restrict__ hpair,
    const float* __restrict__ al, const float* __restrict__ ar,
    float* __restrict__ el, float* __restrict__ er, int Nn){
  int n = blockIdx.x*4 + (threadIdx.x >> 6);
  if (n >= Nn) return;
  int lane = threadIdx.x & 63;
  float4 h = *(const float4*)(hpair + (size_t)n*256 + lane*4);
  float4 a = *(const float4*)(al + lane*4);
  float4 r = *(const float4*)(ar + lane*4);
  float pe = h.x*a.x + h.y*a.y + h.z*a.z + h.w*a.w;
  float pr = h.x*r.x + h.y*r.y + h.z*r.z + h.w*r.w;
  for (int k = 1; k < 32; k <<= 1){ pe += __shfl_xor(pe, k); pr += __shfl_xor(pr, k); }
  if ((lane & 31) == 0){
    int head = lane >> 5;
    el[(size_t)n*2 + head] = pe;
    er[(size_t)n*2 + head] = pr;
  }
}

// ---------------- per-edge leaky-relu scores ----------------
__global__ void k_edge_scores(const float* __restrict__ el, const float* __restrict__ er,
    const int* __restrict__ src, const int* __restrict__ dst, float* __restrict__ escore, int E){
  int e = blockIdx.x*blockDim.x + threadIdx.x;
  if (e >= E) return;
  int s = src[e], d = dst[e];
  float2 l = *(const float2*)(el + (size_t)s*2);
  float2 r = *(const float2*)(er + (size_t)d*2);
  float v0 = l.x + r.x, v1 = l.y + r.y;
  v0 = (v0 > 0.f) ? v0 : 0.2f*v0;
  v1 = (v1 > 0.f) ? v1 : 0.2f*v1;
  float2 o = { v0, v1 };
  *(float2*)(escore + (size_t)e*2) = o;
}

// ---------------- softmax + aggregate (bf16 gather, 2 edges/iter) ----------------
// wave per node. Phase 1/2: lane-parallel max & sum over edges (both heads).
// Phase 3: half = lane>>5 handles edge i+half; sub = lane&31 covers 8 dims of the
// flat 256 (head = sub>>4). Combine halves (xor 32), bias+relu, head-mean (xor 16).
__global__ __launch_bounds__(256) void k_aggregate(const ushort* __restrict__ hpairh,
    const float* __restrict__ escore, const int* __restrict__ src,
    const int* __restrict__ offs, const int* __restrict__ eidx,
    const float* __restrict__ bias, float* __restrict__ out, int Nn){
  int n = blockIdx.x*4 + (threadIdx.x >> 6);
  if (n >= Nn) return;
  int lane = threadIdx.x & 63;
  int e0 = offs[n], e1 = offs[n+1];
  float m0 = -3.4e38f, m1 = -3.4e38f;
  for (int i = e0 + lane; i < e1; i += 64){
    int e = eidx[i];
    float2 sc = *(const float2*)(escore + (size_t)e*2);
    m0 = fmaxf(m0, sc.x); m1 = fmaxf(m1, sc.y);
  }
  for (int k = 1; k < 64; k <<= 1){ m0 = fmaxf(m0, __shfl_xor(m0, k)); m1 = fmaxf(m1, __shfl_xor(m1, k)); }
  float s0 = 0.f, s1 = 0.f;
  for (int i = e0 + lane; i < e1; i += 64){
    int e = eidx[i];
    float2 sc = *(const float2*)(escore + (size_t)e*2);
    s0 += expf(sc.x - m0); s1 += expf(sc.y - m1);
  }
  for (int k = 1; k < 64; k <<= 1){ s0 += __shfl_xor(s0, k); s1 += __shfl_xor(s1, k); }

  int half = lane >> 5;        // which edge of the pair
  int sub  = lane & 31;        // 8-dim slice of flat 256
  int head = sub >> 4;
  float mh  = head ? m1 : m0;
  float invh = head ? (s1 > 0.f ? 1.f/s1 : 0.f) : (s0 > 0.f ? 1.f/s0 : 0.f);

  float acc[8] = {0,0,0,0,0,0,0,0};
  for (int i = e0 + half; i < e1; i += 2){
    int e = eidx[i];
    float w = expf(escore[(size_t)e*2 + head] - mh) * invh;
    uint4 hv = *(const uint4*)(hpairh + (size_t)src[e]*256 + sub*8);
    acc[0] += w * bf_lo(hv.x); acc[1] += w * bf_hi(hv.x);
    acc[2] += w * bf_lo(hv.y); acc[3] += w * bf_hi(hv.y);
    acc[4] += w * bf_lo(hv.z); acc[5] += w * bf_hi(hv.z);
    acc[6] += w * bf_lo(hv.w); acc[7] += w * bf_hi(hv.w);
  }
  #pragma unroll
  for (int k = 0; k < 8; k++) acc[k] += __shfl_xor(acc[k], 32);
  // bias + relu on own flat dims
  float t[8];
  #pragma unroll
  for (int k = 0; k < 8; k++) t[k] = fmaxf(acc[k] + bias[sub*8 + k], 0.f);
  // head-mean: partner is sub^16 (same dim, other head)
  float o[8];
  #pragma unroll
  for (int k = 0; k < 8; k++) o[k] = 0.5f*(t[k] + __shfl_xor(t[k], 16));
  if (lane < 16){
    float4 v0 = { o[0], o[1], o[2], o[3] };
    float4 v1 = { o[4], o[5], o[6], o[7] };
    *(float4*)(out + (size_t)n*128 + sub*8) = v0;
    *(float4*)(out + (size_t)n*128 + sub*8 + 4) = v1;
  }
}

// ---------------- pool gate ----------------
__global__ __launch_bounds__(256) void k_gate(const float* __restrict__ x, const float* __restrict__ gw,
    const float* __restrict__ gb, float* __restrict__ gate, int Nn){
  int n = blockIdx.x*4 + (threadIdx.x >> 6);
  if (n >= Nn) return;
  int lane = threadIdx.x & 63;
  float2 xv = *(const float2*)(x + (size_t)n*128 + lane*2);
  float2 gv = *(const float2*)(gw + lane*2);
  float p = xv.x*gv.x + xv.y*gv.y;
  for (int k = 1; k < 64; k <<= 1) p += __shfl_xor(p, k);
  if (lane == 0) gate[n] = p + gb[0];
}

// ---------------- pool stats ----------------
__global__ __launch_bounds__(256) void k_pool_stats(const float* __restrict__ gate,
    const int* __restrict__ gstart, float* __restrict__ pm, float* __restrict__ psinv){
  int b = blockIdx.x;
  int n0 = gstart[b], n1 = gstart[b+1];
  int tid = threadIdx.x, lane = tid & 63, wid = tid >> 6;
  __shared__ float red[4];
  float m = -3.4e38f;
  for (int n = n0 + tid; n < n1; n += 256) m = fmaxf(m, gate[n]);
  for (int k = 1; k < 64; k <<= 1) m = fmaxf(m, __shfl_xor(m, k));
  if (lane == 0) red[wid] = m;
  __syncthreads();
  m = fmaxf(fmaxf(red[0], red[1]), fmaxf(red[2], red[3]));
  __syncthreads();
  float s = 0.f;
  for (int n = n0 + tid; n < n1; n += 256) s += expf(gate[n] - m);
  for (int k = 1; k < 64; k <<= 1) s += __shfl_xor(s, k);
  if (lane == 0) red[wid] = s;
  __syncthreads();
  if (tid == 0){
    s = red[0] + red[1] + red[2] + red[3];
    pm[b] = m;
    psinv[b] = (s > 0.f) ? 1.f/s : 0.f;
  }
}

// ---------------- pool partial + reduce ----------------
#define POOL_P 32
__global__ __launch_bounds__(128) void k_pool_partial(const float* __restrict__ x,
    const float* __restrict__ gate, const int* __restrict__ gstart,
    const float* __restrict__ pm, const float* __restrict__ psinv,
    float* __restrict__ partials){
  int b = blockIdx.x;
  int p = blockIdx.y;
  int n0 = gstart[b], n1 = gstart[b+1];
  int tid = threadIdx.x;
  float m = pm[b], inv = psinv[b];
  float acc = 0.f;
  for (int n = n0 + p; n < n1; n += POOL_P){
    float w = expf(gate[n] - m) * inv;
    acc += w * x[(size_t)n*128 + tid];
  }
  partials[((size_t)b*POOL_P + p)*128 + tid] = acc;
}

__global__ __launch_bounds__(128) void k_pool_reduce(const float* __restrict__ partials,
    float* __restrict__ hg){
  int b = blockIdx.x;
  int tid = threadIdx.x;
  float s = 0.f;
  #pragma unroll
  for (int p = 0; p < POOL_P; p++) s += partials[((size_t)b*POOL_P + p)*128 + tid];
  hg[(size_t)b*128 + tid] = s;
}

// ---------------- fused LSTM (2 layers x 4 steps) + final head, block per batch row ----------------
__global__ __launch_bounds__(512) void k_lstm_all(const float* __restrict__ seq,
    const float* __restrict__ Wih, const float* __restrict__ Whh,
    const float* __restrict__ bih, const float* __restrict__ bhh,
    const float* __restrict__ cw, const float* __restrict__ cb,
    float* __restrict__ out, int B){
  int b = blockIdx.x;
  int j = threadIdx.x;
  __shared__ float xh[256];       // [x ; h]
  __shared__ float gates[512];
  __shared__ float hcur[128], ccur[128];
  __shared__ float l0out[4][128];
  __shared__ float red[2];

  for (int l = 0; l < 2; l++){
    if (j < 128){ hcur[j] = 0.f; ccur[j] = 0.f; }
    const float* Wi = Wih + (size_t)l*512*128;
    const float* Wh = Whh + (size_t)l*512*128;
    const float* bi = bih + (size_t)l*512;
    const float* bh = bhh + (size_t)l*512;
    __syncthreads();
    for (int t = 0; t < 4; t++){
      if (j < 128) xh[j] = (l == 0) ? seq[(size_t)t*B*128 + (size_t)b*128 + j] : l0out[t][j];
      else if (j < 256) xh[j] = hcur[j - 128];
      __syncthreads();
      float g = bi[j] + bh[j];
      const float4* wi4 = (const float4*)(Wi + (size_t)j*128);
      const float4* wh4 = (const float4*)(Wh + (size_t)j*128);
      #pragma unroll 8
      for (int k = 0; k < 32; k++){
        float4 wi = wi4[k], wh = wh4[k];
        g += xh[4*k+0]*wi.x + xh[4*k+1]*wi.y + xh[4*k+2]*wi.z + xh[4*k+3]*wi.w;
        g += xh[128+4*k+0]*wh.x + xh[128+4*k+1]*wh.y + xh[128+4*k+2]*wh.z + xh[128+4*k+3]*wh.w;
      }
      gates[j] = g;
      __syncthreads();
      if (j < 128){
        float gi = sigmoidf_(gates[j]);
        float gf = sigmoidf_(gates[128 + j]);
        float gg = tanhf(gates[256 + j]);
        float go = sigmoidf_(gates[384 + j]);
        float c = gf * ccur[j] + gi * gg;
        float h = go * tanhf(c);
        ccur[j] = c;
        hcur[j] = h;
        if (l == 0) l0out[t][j] = h;
      }
      __syncthreads();
    }
  }
  // final: sigmoid(dot(hcur, cw) + cb)
  float p = (j < 128) ? hcur[j] * cw[j] : 0.f;
  if (j < 128){
    for (int k = 1; k < 64; k <<= 1) p += __shfl_xor(p, k);
    if ((j & 63) == 0) red[j >> 6] = p;
  }
  __syncthreads();
  if (j == 0) out[b] = sigmoidf_(red[0] + red[1] + cb[0]);
}

extern "C" void kernel_launch(void* const* d_in, const int* in_sizes, int n_in,
                              void* d_out, int out_size, void* d_ws, size_t ws_size,
                              hipStream_t stream){
  const float* nfeats = (const float*)d_in[0];
  const int*   src    = (const int*)d_in[1];
  const int*   dst    = (const int*)d_in[2];
  const int*   ng     = (const int*)d_in[3];
  const float* Wm[3]  = { (const float*)d_in[4],  (const float*)d_in[8],  (const float*)d_in[12] };
  const float* al[3]  = { (const float*)d_in[5],  (const float*)d_in[9],  (const float*)d_in[13] };
  const float* ar[3]  = { (const float*)d_in[6],  (const float*)d_in[10], (const float*)d_in[14] };
  const float* bb[3]  = { (const float*)d_in[7],  (const float*)d_in[11], (const float*)d_in[15] };
  const float* gw[4]  = { (const float*)d_in[16], (const float*)d_in[18], (const float*)d_in[20], (const float*)d_in[22] };
  const float* gb[4]  = { (const float*)d_in[17], (const float*)d_in[19], (const float*)d_in[21], (const float*)d_in[23] };
  const float* Wih = (const float*)d_in[24];
  const float* Whh = (const float*)d_in[25];
  const float* bih = (const float*)d_in[26];
  const float* bhh = (const float*)d_in[27];
  const float* cw  = (const float*)d_in[28];
  const float* cb  = (const float*)d_in[29];

  const int N = in_sizes[3];      // 50000
  const int E = in_sizes[1];      // 800000
  const int B = out_size;         // 64

  char* p = (char*)d_ws;
  auto alloc = [&](size_t bytes) -> void* {
    void* q = (void*)p;
    p += (bytes + 255) & ~(size_t)255;
    return q;
  };
  float*  hpair  = (float*)alloc((size_t)N*256*4);
  ushort* hpairh = (ushort*)alloc((size_t)N*256*2);
  float*  xbuf   = (float*)alloc((size_t)N*128*4);
  float*  el     = (float*)alloc((size_t)N*2*4);
  float*  er     = (float*)alloc((size_t)N*2*4);
  float*  escore = (float*)alloc((size_t)E*2*4);
  float*  gate   = (float*)alloc((size_t)N*4);
  int*    deg    = (int*)alloc((size_t)N*4);
  int*    offs   = (int*)alloc((size_t)(N+1)*4);
  int*    cnt    = (int*)alloc((size_t)N*4);
  int*    eidx   = (int*)alloc((size_t)E*4);
  int*    gstart = (int*)alloc((size_t)(B+1)*4);
  float*  seqA   = (float*)alloc((size_t)4*B*128*4);
  float*  pm     = (float*)alloc((size_t)B*4);
  float*  psinv  = (float*)alloc((size_t)B*4);
  float*  partials = (float*)alloc((size_t)B*POOL_P*128*4);

  auto cdiv = [](int a, int b){ return (a + b - 1) / b; };

  hipMemsetAsync(deg, 0, (size_t)N*4, stream);
  hipMemsetAsync(cnt, 0, (size_t)N*4, stream);
  k_hist<<<cdiv(E,256), 256, 0, stream>>>(dst, deg, E);
  k_exscan<<<1, 256, 0, stream>>>(deg, offs, N);
  k_scatter<<<cdiv(E,256), 256, 0, stream>>>(dst, offs, cnt, eidx, E);
  k_graph_bounds<<<cdiv(N,256), 256, 0, stream>>>(ng, gstart, N, B);

  auto pool = [&](const float* xv, const float* gwv, const float* gbv, float* hgv){
    k_gate<<<cdiv(N,4), 256, 0, stream>>>(xv, gwv, gbv, gate, N);
    k_pool_stats<<<B, 256, 0, stream>>>(gate, gstart, pm, psinv);
    dim3 pg(B, POOL_P);
    k_pool_partial<<<pg, 128, 0, stream>>>(xv, gate, gstart, pm, psinv, partials);
    k_pool_reduce<<<B, 128, 0, stream>>>(partials, hgv);
  };

  pool(nfeats, gw[0], gb[0], seqA + 0*(size_t)B*128);

  const float* x = nfeats;
  for (int layer = 0; layer < 3; layer++){
    dim3 ggrid(cdiv(N,64), 4);
    k_gemm<<<ggrid, 256, 0, stream>>>(x, Wm[layer], hpair, hpairh, N);
    k_node_scores<<<cdiv(N,4), 256, 0, stream>>>(hpair, al[layer], ar[layer], el, er, N);
    k_edge_scores<<<cdiv(E,256), 256, 0, stream>>>(el, er, src, dst, escore, E);
    k_aggregate<<<cdiv(N,4), 256, 0, stream>>>(hpairh, escore, src, offs, eidx, bb[layer], xbuf, N);
    x = xbuf;
    pool(x, gw[layer+1], gb[layer+1], seqA + (size_t)(layer+1)*B*128);
  }

  k_lstm_all<<<B, 512, 0, stream>>>(seqA, Wih, Whh, bih, bhh, cw, cb, (float*)d_out, B);
}

// Round 5
// 754.557 us; speedup vs baseline: 2.4659x; 1.2547x over previous
//
#include <hip/hip_runtime.h>
#include <cmath>

// N=50000 nodes, E=800000 edges, B=64 graphs, H=2 heads, D=128, FIN=128, L=2.

typedef __attribute__((ext_vector_type(8))) short short8v;   // 8 x bf16 (4 VGPRs)
typedef __attribute__((ext_vector_type(4))) float float4v;   // MFMA acc

__device__ __forceinline__ float sigmoidf_(float x){ return 1.f/(1.f+expf(-x)); }

__device__ __forceinline__ unsigned f2bf_rne(float f){
  unsigned u = __float_as_uint(f);
  return (u + 0x7fffu + ((u >> 16) & 1u)) >> 16;   // round-nearest-even bf16
}
__device__ __forceinline__ float bf_lo(unsigned u){ return __uint_as_float(u << 16); }
__device__ __forceinline__ float bf_hi(unsigned u){ return __uint_as_float(u & 0xffff0000u); }

// ---------------- CSR build (by dst) ----------------
__global__ void k_hist(const int* __restrict__ dst, int* __restrict__ deg, int E){
  int e = blockIdx.x*blockDim.x + threadIdx.x;
  if (e < E) atomicAdd(&deg[dst[e]], 1);
}

// parallel exclusive scan: chunk sums -> tiny scan -> apply
#define CHUNK 1024
__global__ __launch_bounds__(256) void k_chunksum(const int* __restrict__ in, int* __restrict__ csum, int n){
  int b = blockIdx.x;
  int tid = threadIdx.x;
  int v = 0;
  #pragma unroll
  for (int k = 0; k < 4; k++){
    int i = b*CHUNK + tid + k*256;
    if (i < n) v += in[i];
  }
  for (int d = 1; d < 64; d <<= 1) v += __shfl_xor(v, d);
  __shared__ int ws[4];
  if ((tid & 63) == 0) ws[tid>>6] = v;
  __syncthreads();
  if (tid == 0) csum[b] = ws[0]+ws[1]+ws[2]+ws[3];
}

__global__ void k_scan_small(const int* __restrict__ csum, int* __restrict__ cpre, int nb,
                             int* __restrict__ total_out){
  int lane = threadIdx.x;  // 64 threads, nb <= 64
  int v = (lane < nb) ? csum[lane] : 0;
  int incl = v;
  for (int d = 1; d < 64; d <<= 1){ int t = __shfl_up(incl, d); if (lane >= d) incl += t; }
  if (lane < nb) cpre[lane] = incl - v;
  if (lane == 63) *total_out = incl;
}

__global__ __launch_bounds__(256) void k_scan_apply(const int* __restrict__ in, const int* __restrict__ cpre,
                                                    int* __restrict__ offs, int n){
  int b = blockIdx.x;
  int tid = threadIdx.x, lane = tid & 63, wid = tid >> 6;
  int x[4];
  int s = 0;
  #pragma unroll
  for (int k = 0; k < 4; k++){
    int i = b*CHUNK + tid*4 + k;
    x[k] = (i < n) ? in[i] : 0;
    s += x[k];
  }
  int incl = s;
  for (int d = 1; d < 64; d <<= 1){ int t = __shfl_up(incl, d); if (lane >= d) incl += t; }
  __shared__ int ws[4];
  if (lane == 63) ws[wid] = incl;
  __syncthreads();
  int wpre = 0;
  for (int w = 0; w < wid; w++) wpre += ws[w];
  int base = cpre[b] + wpre + incl - s;
  #pragma unroll
  for (int k = 0; k < 4; k++){
    int i = b*CHUNK + tid*4 + k;
    if (i < n) offs[i] = base;
    base += x[k];
  }
}

__global__ void k_scatter(const int* __restrict__ dst, const int* __restrict__ offs,
                          int* __restrict__ cnt, int* __restrict__ eidx, int E){
  int e = blockIdx.x*blockDim.x + threadIdx.x;
  if (e < E){ int d = dst[e]; int p = atomicAdd(&cnt[d], 1); eidx[offs[d] + p] = e; }
}

__global__ void k_graph_bounds(const int* __restrict__ ng, int* __restrict__ gstart, int n, int nb){
  int i = blockIdx.x*blockDim.x + threadIdx.x;
  if (i >= n) return;
  int g = ng[i];
  int gp = (i == 0) ? -1 : ng[i-1];
  for (int b = gp+1; b <= g; b++) gstart[b] = i;
  if (i == n-1) for (int b = g+1; b <= nb; b++) gstart[b] = n;
}

// ---------------- conversions ----------------
__global__ void k_tobf16(const float* __restrict__ in, ushort* __restrict__ out, int n8){
  int i = blockIdx.x*blockDim.x + threadIdx.x;
  if (i >= n8) return;
  float4 a = *(const float4*)(in + (size_t)i*8);
  float4 b = *(const float4*)(in + (size_t)i*8 + 4);
  ushort u[8] = { (ushort)f2bf_rne(a.x), (ushort)f2bf_rne(a.y), (ushort)f2bf_rne(a.z), (ushort)f2bf_rne(a.w),
                  (ushort)f2bf_rne(b.x), (ushort)f2bf_rne(b.y), (ushort)f2bf_rne(b.z), (ushort)f2bf_rne(b.w) };
  *(uint4*)(out + (size_t)i*8) = *(uint4*)u;
}

// W [128,256] f32 -> Wt [256,128] bf16
__global__ void k_wt(const float* __restrict__ W, ushort* __restrict__ Wt, int total){
  int idx = blockIdx.x*blockDim.x + threadIdx.x;
  if (idx >= total) return;
  int c = idx >> 7;
  int k = idx & 127;
  Wt[idx] = (ushort)f2bf_rne(W[(size_t)k*256 + c]);
}

// ---------------- MFMA GEMM: Yh[M,256](bf16) = Xh[M,128] @ W, fused el/er ----------------
// wave per 16-row strip, all 256 cols. A row=lane&15,k=(lane>>4)*8+j; B col=lane&15 (from Wt);
// C/D col=lane&15, row=(lane>>4)*4+reg  [guide m89-verified].
__global__ __launch_bounds__(256) void k_gemm_mfma(const ushort* __restrict__ Xh,
    const ushort* __restrict__ Wt, const float* __restrict__ alv, const float* __restrict__ arv,
    ushort* __restrict__ Yh, float* __restrict__ el, float* __restrict__ er, int M){
  int wave = threadIdx.x >> 6;
  int lane = threadIdx.x & 63;
  int strip = blockIdx.x*4 + wave;
  if (strip*16 >= M) return;
  int m0 = strip*16;
  int l15 = lane & 15;
  int kg  = lane >> 4;
  int arow = m0 + l15; if (arow >= M) arow = M-1;   // clamp (M%16==0 here anyway)
  short8v a[4];
  const ushort* xrow = Xh + (size_t)arow*128 + kg*8;
  #pragma unroll
  for (int ks = 0; ks < 4; ks++) a[ks] = *(const short8v*)(xrow + ks*32);
  float4v acc[16];
  #pragma unroll
  for (int nt = 0; nt < 16; nt++) acc[nt] = (float4v){0.f,0.f,0.f,0.f};
  #pragma unroll
  for (int nt = 0; nt < 16; nt++){
    const ushort* wrow = Wt + (size_t)(nt*16 + l15)*128 + kg*8;
    #pragma unroll
    for (int ks = 0; ks < 4; ks++){
      short8v b = *(const short8v*)(wrow + ks*32);
      acc[nt] = __builtin_amdgcn_mfma_f32_16x16x32_bf16(a[ks], b, acc[nt], 0, 0, 0);
    }
  }
  float pel0[4]={0,0,0,0}, pel1[4]={0,0,0,0}, per0[4]={0,0,0,0}, per1[4]={0,0,0,0};
  #pragma unroll
  for (int nt = 0; nt < 16; nt++){
    int col = nt*16 + l15;
    float av = alv[col], rv = arv[col];
    #pragma unroll
    for (int j = 0; j < 4; j++){
      float v = acc[nt][j];
      int r = m0 + kg*4 + j;
      if (r < M) Yh[(size_t)r*256 + col] = (ushort)f2bf_rne(v);
      if (nt < 8){ pel0[j] += v*av; per0[j] += v*rv; }
      else       { pel1[j] += v*av; per1[j] += v*rv; }
    }
  }
  #pragma unroll
  for (int j = 0; j < 4; j++){
    #pragma unroll
    for (int d = 1; d < 16; d <<= 1){
      pel0[j] += __shfl_xor(pel0[j], d);
      pel1[j] += __shfl_xor(pel1[j], d);
      per0[j] += __shfl_xor(per0[j], d);
      per1[j] += __shfl_xor(per1[j], d);
    }
  }
  if (l15 == 0){
    #pragma unroll
    for (int j = 0; j < 4; j++){
      int r = m0 + kg*4 + j;
      if (r < M){
        el[(size_t)r*2+0] = pel0[j];
        el[(size_t)r*2+1] = pel1[j];
        er[(size_t)r*2+0] = per0[j];
        er[(size_t)r*2+1] = per1[j];
      }
    }
  }
}

// ---------------- per-edge leaky-relu scores ----------------
__global__ void k_edge_scores(const float* __restrict__ el, const float* __restrict__ er,
    const int* __restrict__ src, const int* __restrict__ dst, float* __restrict__ escore, int E){
  int e = blockIdx.x*blockDim.x + threadIdx.x;
  if (e >= E) return;
  int s = src[e], d = dst[e];
  float2 l = *(const float2*)(el + (size_t)s*2);
  float2 r = *(const float2*)(er + (size_t)d*2);
  float v0 = l.x + r.x, v1 = l.y + r.y;
  v0 = (v0 > 0.f) ? v0 : 0.2f*v0;
  v1 = (v1 > 0.f) ? v1 : 0.2f*v1;
  float2 o = { v0, v1 };
  *(float2*)(escore + (size_t)e*2) = o;
}

// ---------------- softmax + aggregate + bias/relu/head-mean + fused gate + bf16 out ----------------
__global__ __launch_bounds__(256) void k_aggregate(const ushort* __restrict__ hpairh,
    const float* __restrict__ escore, const int* __restrict__ src,
    const int* __restrict__ offs, const int* __restrict__ eidx,
    const float* __restrict__ bias, const float* __restrict__ gwv, const float* __restrict__ gbv,
    float* __restrict__ out, ushort* __restrict__ outh, float* __restrict__ gate, int Nn){
  int n = blockIdx.x*4 + (threadIdx.x >> 6);
  if (n >= Nn) return;
  int lane = threadIdx.x & 63;
  int e0 = offs[n], e1 = offs[n+1];
  float m0 = -3.4e38f, m1 = -3.4e38f;
  for (int i = e0 + lane; i < e1; i += 64){
    int e = eidx[i];
    float2 sc = *(const float2*)(escore + (size_t)e*2);
    m0 = fmaxf(m0, sc.x); m1 = fmaxf(m1, sc.y);
  }
  for (int k = 1; k < 64; k <<= 1){ m0 = fmaxf(m0, __shfl_xor(m0, k)); m1 = fmaxf(m1, __shfl_xor(m1, k)); }
  float s0 = 0.f, s1 = 0.f;
  for (int i = e0 + lane; i < e1; i += 64){
    int e = eidx[i];
    float2 sc = *(const float2*)(escore + (size_t)e*2);
    s0 += expf(sc.x - m0); s1 += expf(sc.y - m1);
  }
  for (int k = 1; k < 64; k <<= 1){ s0 += __shfl_xor(s0, k); s1 += __shfl_xor(s1, k); }

  int half = lane >> 5;        // which edge of the pair
  int sub  = lane & 31;        // 8-dim slice of flat 256
  int head = sub >> 4;
  float mh  = head ? m1 : m0;
  float invh = head ? (s1 > 0.f ? 1.f/s1 : 0.f) : (s0 > 0.f ? 1.f/s0 : 0.f);

  float acc[8] = {0,0,0,0,0,0,0,0};
  for (int i = e0 + half; i < e1; i += 2){
    int e = eidx[i];
    float w = expf(escore[(size_t)e*2 + head] - mh) * invh;
    uint4 hv = *(const uint4*)(hpairh + (size_t)src[e]*256 + sub*8);
    acc[0] += w * bf_lo(hv.x); acc[1] += w * bf_hi(hv.x);
    acc[2] += w * bf_lo(hv.y); acc[3] += w * bf_hi(hv.y);
    acc[4] += w * bf_lo(hv.z); acc[5] += w * bf_hi(hv.z);
    acc[6] += w * bf_lo(hv.w); acc[7] += w * bf_hi(hv.w);
  }
  #pragma unroll
  for (int k = 0; k < 8; k++) acc[k] += __shfl_xor(acc[k], 32);
  float t[8];
  #pragma unroll
  for (int k = 0; k < 8; k++) t[k] = fmaxf(acc[k] + bias[sub*8 + k], 0.f);
  float o[8];
  #pragma unroll
  for (int k = 0; k < 8; k++) o[k] = 0.5f*(t[k] + __shfl_xor(t[k], 16));
  if (lane < 16){
    float4 v0 = { o[0], o[1], o[2], o[3] };
    float4 v1 = { o[4], o[5], o[6], o[7] };
    *(float4*)(out + (size_t)n*128 + sub*8) = v0;
    *(float4*)(out + (size_t)n*128 + sub*8 + 4) = v1;
    ushort u[8] = { (ushort)f2bf_rne(o[0]), (ushort)f2bf_rne(o[1]), (ushort)f2bf_rne(o[2]), (ushort)f2bf_rne(o[3]),
                    (ushort)f2bf_rne(o[4]), (ushort)f2bf_rne(o[5]), (ushort)f2bf_rne(o[6]), (ushort)f2bf_rne(o[7]) };
    *(uint4*)(outh + (size_t)n*128 + sub*8) = *(uint4*)u;
    float gp = 0.f;
    #pragma unroll
    for (int k = 0; k < 8; k++) gp += o[k]*gwv[sub*8 + k];
    #pragma unroll
    for (int d = 1; d < 16; d <<= 1) gp += __shfl_xor(gp, d);
    if (sub == 0) gate[n] = gp + gbv[0];
  }
}

// ---------------- pool gate (only for layer-0 input) ----------------
__global__ __launch_bounds__(256) void k_gate(const float* __restrict__ x, const float* __restrict__ gw,
    const float* __restrict__ gb, float* __restrict__ gate, int Nn){
  int n = blockIdx.x*4 + (threadIdx.x >> 6);
  if (n >= Nn) return;
  int lane = threadIdx.x & 63;
  float2 xv = *(const float2*)(x + (size_t)n*128 + lane*2);
  float2 gv = *(const float2*)(gw + lane*2);
  float p = xv.x*gv.x + xv.y*gv.y;
  for (int k = 1; k < 64; k <<= 1) p += __shfl_xor(p, k);
  if (lane == 0) gate[n] = p + gb[0];
}

// ---------------- pool stats ----------------
__global__ __launch_bounds__(256) void k_pool_stats(const float* __restrict__ gate,
    const int* __restrict__ gstart, float* __restrict__ pm, float* __restrict__ psinv){
  int b = blockIdx.x;
  int n0 = gstart[b], n1 = gstart[b+1];
  int tid = threadIdx.x, lane = tid & 63, wid = tid >> 6;
  __shared__ float red[4];
  float m = -3.4e38f;
  for (int n = n0 + tid; n < n1; n += 256) m = fmaxf(m, gate[n]);
  for (int k = 1; k < 64; k <<= 1) m = fmaxf(m, __shfl_xor(m, k));
  if (lane == 0) red[wid] = m;
  __syncthreads();
  m = fmaxf(fmaxf(red[0], red[1]), fmaxf(red[2], red[3]));
  __syncthreads();
  float s = 0.f;
  for (int n = n0 + tid; n < n1; n += 256) s += expf(gate[n] - m);
  for (int k = 1; k < 64; k <<= 1) s += __shfl_xor(s, k);
  if (lane == 0) red[wid] = s;
  __syncthreads();
  if (tid == 0){
    s = red[0] + red[1] + red[2] + red[3];
    pm[b] = m;
    psinv[b] = (s > 0.f) ? 1.f/s : 0.f;
  }
}

// ---------------- pool partial + reduce ----------------
#define POOL_P 32
__global__ __launch_bounds__(128) void k_pool_partial(const float* __restrict__ x,
    const float* __restrict__ gate, const int* __restrict__ gstart,
    const float* __restrict__ pm, const float* __restrict__ psinv,
    float* __restrict__ partials){
  int b = blockIdx.x;
  int p = blockIdx.y;
  int n0 = gstart[b], n1 = gstart[b+1];
  int tid = threadIdx.x;
  float m = pm[b], inv = psinv[b];
  float acc = 0.f;
  for (int n = n0 + p; n < n1; n += POOL_P){
    float w = expf(gate[n] - m) * inv;
    acc += w * x[(size_t)n*128 + tid];
  }
  partials[((size_t)b*POOL_P + p)*128 + tid] = acc;
}

__global__ __launch_bounds__(128) void k_pool_reduce(const float* __restrict__ partials,
    float* __restrict__ hg){
  int b = blockIdx.x;
  int tid = threadIdx.x;
  float s = 0.f;
  #pragma unroll
  for (int p = 0; p < POOL_P; p++) s += partials[((size_t)b*POOL_P + p)*128 + tid];
  hg[(size_t)b*128 + tid] = s;
}

// ---------------- fused LSTM (2 layers x 4 steps) + final head, block per batch row ----------------
__global__ __launch_bounds__(512) void k_lstm_all(const float* __restrict__ seq,
    const float* __restrict__ Wih, const float* __restrict__ Whh,
    const float* __restrict__ bih, const float* __restrict__ bhh,
    const float* __restrict__ cw, const float* __restrict__ cb,
    float* __restrict__ out, int B){
  int b = blockIdx.x;
  int j = threadIdx.x;
  __shared__ float xh[256];
  __shared__ float gates[512];
  __shared__ float hcur[128], ccur[128];
  __shared__ float l0out[4][128];
  __shared__ float red[2];

  for (int l = 0; l < 2; l++){
    if (j < 128){ hcur[j] = 0.f; ccur[j] = 0.f; }
    const float* Wi = Wih + (size_t)l*512*128;
    const float* Wh = Whh + (size_t)l*512*128;
    const float* bi = bih + (size_t)l*512;
    const float* bh = bhh + (size_t)l*512;
    __syncthreads();
    for (int t = 0; t < 4; t++){
      if (j < 128) xh[j] = (l == 0) ? seq[(size_t)t*B*128 + (size_t)b*128 + j] : l0out[t][j];
      else if (j < 256) xh[j] = hcur[j - 128];
      __syncthreads();
      float g = bi[j] + bh[j];
      const float4* wi4 = (const float4*)(Wi + (size_t)j*128);
      const float4* wh4 = (const float4*)(Wh + (size_t)j*128);
      #pragma unroll 8
      for (int k = 0; k < 32; k++){
        float4 wi = wi4[k], wh = wh4[k];
        g += xh[4*k+0]*wi.x + xh[4*k+1]*wi.y + xh[4*k+2]*wi.z + xh[4*k+3]*wi.w;
        g += xh[128+4*k+0]*wh.x + xh[128+4*k+1]*wh.y + xh[128+4*k+2]*wh.z + xh[128+4*k+3]*wh.w;
      }
      gates[j] = g;
      __syncthreads();
      if (j < 128){
        float gi = sigmoidf_(gates[j]);
        float gf = sigmoidf_(gates[128 + j]);
        float gg = tanhf(gates[256 + j]);
        float go = sigmoidf_(gates[384 + j]);
        float c = gf * ccur[j] + gi * gg;
        float h = go * tanhf(c);
        ccur[j] = c;
        hcur[j] = h;
        if (l == 0) l0out[t][j] = h;
      }
      __syncthreads();
    }
  }
  float p = (j < 128) ? hcur[j] * cw[j] : 0.f;
  if (j < 128){
    for (int k = 1; k < 64; k <<= 1) p += __shfl_xor(p, k);
    if ((j & 63) == 0) red[j >> 6] = p;
  }
  __syncthreads();
  if (j == 0) out[b] = sigmoidf_(red[0] + red[1] + cb[0]);
}

extern "C" void kernel_launch(void* const* d_in, const int* in_sizes, int n_in,
                              void* d_out, int out_size, void* d_ws, size_t ws_size,
                              hipStream_t stream){
  const float* nfeats = (const float*)d_in[0];
  const int*   src    = (const int*)d_in[1];
  const int*   dst    = (const int*)d_in[2];
  const int*   ng     = (const int*)d_in[3];
  const float* Wm[3]  = { (const float*)d_in[4],  (const float*)d_in[8],  (const float*)d_in[12] };
  const float* al[3]  = { (const float*)d_in[5],  (const float*)d_in[9],  (const float*)d_in[13] };
  const float* ar[3]  = { (const float*)d_in[6],  (const float*)d_in[10], (const float*)d_in[14] };
  const float* bb[3]  = { (const float*)d_in[7],  (const float*)d_in[11], (const float*)d_in[15] };
  const float* gw[4]  = { (const float*)d_in[16], (const float*)d_in[18], (const float*)d_in[20], (const float*)d_in[22] };
  const float* gb[4]  = { (const float*)d_in[17], (const float*)d_in[19], (const float*)d_in[21], (const float*)d_in[23] };
  const float* Wih = (const float*)d_in[24];
  const float* Whh = (const float*)d_in[25];
  const float* bih = (const float*)d_in[26];
  const float* bhh = (const float*)d_in[27];
  const float* cw  = (const float*)d_in[28];
  const float* cb  = (const float*)d_in[29];

  const int N = in_sizes[3];      // 50000
  const int E = in_sizes[1];      // 800000
  const int B = out_size;         // 64

  char* p = (char*)d_ws;
  auto alloc = [&](size_t bytes) -> void* {
    void* q = (void*)p;
    p += (bytes + 255) & ~(size_t)255;
    return q;
  };
  ushort* hpairh = (ushort*)alloc((size_t)N*256*2);
  float*  xbuf   = (float*)alloc((size_t)N*128*4);
  ushort* aggh   = (ushort*)alloc((size_t)N*128*2);
  ushort* xh0    = (ushort*)alloc((size_t)N*128*2);
  ushort* Wt     = (ushort*)alloc((size_t)3*256*128*2);
  float*  el     = (float*)alloc((size_t)N*2*4);
  float*  er     = (float*)alloc((size_t)N*2*4);
  float*  escore = (float*)alloc((size_t)E*2*4);
  float*  gate   = (float*)alloc((size_t)N*4);
  int*    deg    = (int*)alloc((size_t)N*4);
  int*    offs   = (int*)alloc((size_t)(N+1)*4);
  int*    cnt    = (int*)alloc((size_t)N*4);
  int*    eidx   = (int*)alloc((size_t)E*4);
  int*    gstart = (int*)alloc((size_t)(B+1)*4);
  int*    csum   = (int*)alloc((size_t)64*4);
  int*    cpre   = (int*)alloc((size_t)64*4);
  float*  seqA   = (float*)alloc((size_t)4*B*128*4);
  float*  pm     = (float*)alloc((size_t)B*4);
  float*  psinv  = (float*)alloc((size_t)B*4);
  float*  partials = (float*)alloc((size_t)B*POOL_P*128*4);

  auto cdiv = [](int a, int b){ return (a + b - 1) / b; };
  const int NB = cdiv(N, CHUNK);   // 49 chunks

  hipMemsetAsync(deg, 0, (size_t)N*4, stream);
  hipMemsetAsync(cnt, 0, (size_t)N*4, stream);
  k_hist<<<cdiv(E,256), 256, 0, stream>>>(dst, deg, E);
  k_chunksum<<<NB, 256, 0, stream>>>(deg, csum, N);
  k_scan_small<<<1, 64, 0, stream>>>(csum, cpre, NB, offs + N);
  k_scan_apply<<<NB, 256, 0, stream>>>(deg, cpre, offs, N);
  k_scatter<<<cdiv(E,256), 256, 0, stream>>>(dst, offs, cnt, eidx, E);
  k_graph_bounds<<<cdiv(N,256), 256, 0, stream>>>(ng, gstart, N, B);

  // conversions
  k_tobf16<<<cdiv(N*16, 256), 256, 0, stream>>>(nfeats, xh0, N*16);   // N*128/8
  for (int l = 0; l < 3; l++)
    k_wt<<<cdiv(256*128, 256), 256, 0, stream>>>(Wm[l], Wt + (size_t)l*256*128, 256*128);

  auto pool_rest = [&](const float* xv, float* hgv){
    k_pool_stats<<<B, 256, 0, stream>>>(gate, gstart, pm, psinv);
    dim3 pg(B, POOL_P);
    k_pool_partial<<<pg, 128, 0, stream>>>(xv, gate, gstart, pm, psinv, partials);
    k_pool_reduce<<<B, 128, 0, stream>>>(partials, hgv);
  };

  // pool 0 on raw features
  k_gate<<<cdiv(N,4), 256, 0, stream>>>(nfeats, gw[0], gb[0], gate, N);
  pool_rest(nfeats, seqA + 0*(size_t)B*128);

  const ushort* xh = xh0;
  const int strips = cdiv(N, 16);
  for (int layer = 0; layer < 3; layer++){
    k_gemm_mfma<<<cdiv(strips,4), 256, 0, stream>>>(xh, Wt + (size_t)layer*256*128,
        al[layer], ar[layer], hpairh, el, er, N);
    k_edge_scores<<<cdiv(E,256), 256, 0, stream>>>(el, er, src, dst, escore, E);
    k_aggregate<<<cdiv(N,4), 256, 0, stream>>>(hpairh, escore, src, offs, eidx,
        bb[layer], gw[layer+1], gb[layer+1], xbuf, aggh, gate, N);
    pool_rest(xbuf, seqA + (size_t)(layer+1)*B*128);
    xh = aggh;
  }

  k_lstm_all<<<B, 512, 0, stream>>>(seqA, Wih, Whh, bih, bhh, cw, cb, (float*)d_out, B);
}

// Round 6
// 699.549 us; speedup vs baseline: 2.6598x; 1.0786x over previous
//
#include <hip/hip_runtime.h>
#include <cmath>

// N=50000 nodes, E=800000 edges, B=64 graphs, H=2 heads, D=128, FIN=128, L=2.

typedef __attribute__((ext_vector_type(8))) short short8v;   // 8 x bf16 (4 VGPRs)
typedef __attribute__((ext_vector_type(4))) float float4v;   // MFMA acc

__device__ __forceinline__ float sigmoidf_(float x){ return 1.f/(1.f+expf(-x)); }

__device__ __forceinline__ unsigned f2bf_rne(float f){
  unsigned u = __float_as_uint(f);
  return (u + 0x7fffu + ((u >> 16) & 1u)) >> 16;   // round-nearest-even bf16
}
__device__ __forceinline__ float bf_lo(unsigned u){ return __uint_as_float(u << 16); }
__device__ __forceinline__ float bf_hi(unsigned u){ return __uint_as_float(u & 0xffff0000u); }

// ---------------- CSR build (by dst) ----------------
__global__ void k_hist(const int* __restrict__ dst, int* __restrict__ deg, int E){
  int e = blockIdx.x*blockDim.x + threadIdx.x;
  if (e < E) atomicAdd(&deg[dst[e]], 1);
}

// parallel exclusive scan: chunk sums -> tiny scan -> apply
#define CHUNK 1024
__global__ __launch_bounds__(256) void k_chunksum(const int* __restrict__ in, int* __restrict__ csum, int n){
  int b = blockIdx.x;
  int tid = threadIdx.x;
  int v = 0;
  #pragma unroll
  for (int k = 0; k < 4; k++){
    int i = b*CHUNK + tid + k*256;
    if (i < n) v += in[i];
  }
  for (int d = 1; d < 64; d <<= 1) v += __shfl_xor(v, d);
  __shared__ int ws[4];
  if ((tid & 63) == 0) ws[tid>>6] = v;
  __syncthreads();
  if (tid == 0) csum[b] = ws[0]+ws[1]+ws[2]+ws[3];
}

__global__ void k_scan_small(const int* __restrict__ csum, int* __restrict__ cpre, int nb,
                             int* __restrict__ total_out){
  int lane = threadIdx.x;  // 64 threads, nb <= 64
  int v = (lane < nb) ? csum[lane] : 0;
  int incl = v;
  for (int d = 1; d < 64; d <<= 1){ int t = __shfl_up(incl, d); if (lane >= d) incl += t; }
  if (lane < nb) cpre[lane] = incl - v;
  if (lane == 63) *total_out = incl;
}

__global__ __launch_bounds__(256) void k_scan_apply(const int* __restrict__ in, const int* __restrict__ cpre,
                                                    int* __restrict__ offs, int n){
  int b = blockIdx.x;
  int tid = threadIdx.x, lane = tid & 63, wid = tid >> 6;
  int x[4];
  int s = 0;
  #pragma unroll
  for (int k = 0; k < 4; k++){
    int i = b*CHUNK + tid*4 + k;
    x[k] = (i < n) ? in[i] : 0;
    s += x[k];
  }
  int incl = s;
  for (int d = 1; d < 64; d <<= 1){ int t = __shfl_up(incl, d); if (lane >= d) incl += t; }
  __shared__ int ws[4];
  if (lane == 63) ws[wid] = incl;
  __syncthreads();
  int wpre = 0;
  for (int w = 0; w < wid; w++) wpre += ws[w];
  int base = cpre[b] + wpre + incl - s;
  #pragma unroll
  for (int k = 0; k < 4; k++){
    int i = b*CHUNK + tid*4 + k;
    if (i < n) offs[i] = base;
    base += x[k];
  }
}

__global__ void k_scatter(const int* __restrict__ dst, const int* __restrict__ offs,
                          int* __restrict__ cnt, int* __restrict__ eidx, int E){
  int e = blockIdx.x*blockDim.x + threadIdx.x;
  if (e < E){ int d = dst[e]; int p = atomicAdd(&cnt[d], 1); eidx[offs[d] + p] = e; }
}

__global__ void k_graph_bounds(const int* __restrict__ ng, int* __restrict__ gstart, int n, int nb){
  int i = blockIdx.x*blockDim.x + threadIdx.x;
  if (i >= n) return;
  int g = ng[i];
  int gp = (i == 0) ? -1 : ng[i-1];
  for (int b = gp+1; b <= g; b++) gstart[b] = i;
  if (i == n-1) for (int b = g+1; b <= nb; b++) gstart[b] = n;
}

// ---------------- conversions ----------------
__global__ void k_tobf16(const float* __restrict__ in, ushort* __restrict__ out, int n8){
  int i = blockIdx.x*blockDim.x + threadIdx.x;
  if (i >= n8) return;
  float4 a = *(const float4*)(in + (size_t)i*8);
  float4 b = *(const float4*)(in + (size_t)i*8 + 4);
  ushort u[8] = { (ushort)f2bf_rne(a.x), (ushort)f2bf_rne(a.y), (ushort)f2bf_rne(a.z), (ushort)f2bf_rne(a.w),
                  (ushort)f2bf_rne(b.x), (ushort)f2bf_rne(b.y), (ushort)f2bf_rne(b.z), (ushort)f2bf_rne(b.w) };
  *(uint4*)(out + (size_t)i*8) = *(uint4*)u;
}

// W [128,256] f32 -> Wt [256,128] bf16
__global__ void k_wt(const float* __restrict__ W, ushort* __restrict__ Wt, int total){
  int idx = blockIdx.x*blockDim.x + threadIdx.x;
  if (idx >= total) return;
  int c = idx >> 7;
  int k = idx & 127;
  Wt[idx] = (ushort)f2bf_rne(W[(size_t)k*256 + c]);
}

// LSTM weight prep: WT[l][k][j] (k=0..255: x then h; j gate) + combined bias
__global__ void k_lstm_prep(const float* __restrict__ Wih, const float* __restrict__ Whh,
                            const float* __restrict__ bih, const float* __restrict__ bhh,
                            float* __restrict__ WT, float* __restrict__ bias2){
  int idx = blockIdx.x*blockDim.x + threadIdx.x;   // 2*256*512
  if (idx >= 2*256*512) return;
  int l = idx >> 17;
  int r = idx & 131071;
  int k = r >> 9;
  int j = r & 511;
  float v = (k < 128) ? Wih[(size_t)l*512*128 + (size_t)j*128 + k]
                      : Whh[(size_t)l*512*128 + (size_t)j*128 + (k-128)];
  WT[idx] = v;
  if (k == 0) bias2[l*512 + j] = bih[l*512 + j] + bhh[l*512 + j];
}

// ---------------- MFMA GEMM: Yh[M,256](bf16) = Xh[M,128] @ W, fused el/er ----------------
// wave per 16-row strip, all 256 cols. A row=lane&15,k=(lane>>4)*8+j; B col=lane&15 (from Wt);
// C/D col=lane&15, row=(lane>>4)*4+reg  [guide m89-verified].
__global__ __launch_bounds__(256) void k_gemm_mfma(const ushort* __restrict__ Xh,
    const ushort* __restrict__ Wt, const float* __restrict__ alv, const float* __restrict__ arv,
    ushort* __restrict__ Yh, float* __restrict__ el, float* __restrict__ er, int M){
  int wave = threadIdx.x >> 6;
  int lane = threadIdx.x & 63;
  int strip = blockIdx.x*4 + wave;
  if (strip*16 >= M) return;
  int m0 = strip*16;
  int l15 = lane & 15;
  int kg  = lane >> 4;
  int arow = m0 + l15; if (arow >= M) arow = M-1;
  short8v a[4];
  const ushort* xrow = Xh + (size_t)arow*128 + kg*8;
  #pragma unroll
  for (int ks = 0; ks < 4; ks++) a[ks] = *(const short8v*)(xrow + ks*32);
  float4v acc[16];
  #pragma unroll
  for (int nt = 0; nt < 16; nt++) acc[nt] = (float4v){0.f,0.f,0.f,0.f};
  #pragma unroll
  for (int nt = 0; nt < 16; nt++){
    const ushort* wrow = Wt + (size_t)(nt*16 + l15)*128 + kg*8;
    #pragma unroll
    for (int ks = 0; ks < 4; ks++){
      short8v b = *(const short8v*)(wrow + ks*32);
      acc[nt] = __builtin_amdgcn_mfma_f32_16x16x32_bf16(a[ks], b, acc[nt], 0, 0, 0);
    }
  }
  float pel0[4]={0,0,0,0}, pel1[4]={0,0,0,0}, per0[4]={0,0,0,0}, per1[4]={0,0,0,0};
  #pragma unroll
  for (int nt = 0; nt < 16; nt++){
    int col = nt*16 + l15;
    float av = alv[col], rv = arv[col];
    #pragma unroll
    for (int j = 0; j < 4; j++){
      float v = acc[nt][j];
      int r = m0 + kg*4 + j;
      if (r < M) Yh[(size_t)r*256 + col] = (ushort)f2bf_rne(v);
      if (nt < 8){ pel0[j] += v*av; per0[j] += v*rv; }
      else       { pel1[j] += v*av; per1[j] += v*rv; }
    }
  }
  #pragma unroll
  for (int j = 0; j < 4; j++){
    #pragma unroll
    for (int d = 1; d < 16; d <<= 1){
      pel0[j] += __shfl_xor(pel0[j], d);
      pel1[j] += __shfl_xor(pel1[j], d);
      per0[j] += __shfl_xor(per0[j], d);
      per1[j] += __shfl_xor(per1[j], d);
    }
  }
  if (l15 == 0){
    #pragma unroll
    for (int j = 0; j < 4; j++){
      int r = m0 + kg*4 + j;
      if (r < M){
        el[(size_t)r*2+0] = pel0[j];
        el[(size_t)r*2+1] = pel1[j];
        er[(size_t)r*2+0] = per0[j];
        er[(size_t)r*2+1] = per1[j];
      }
    }
  }
}

// ---------------- per-edge leaky-relu scores ----------------
__global__ void k_edge_scores(const float* __restrict__ el, const float* __restrict__ er,
    const int* __restrict__ src, const int* __restrict__ dst, float* __restrict__ escore, int E){
  int e = blockIdx.x*blockDim.x + threadIdx.x;
  if (e >= E) return;
  int s = src[e], d = dst[e];
  float2 l = *(const float2*)(el + (size_t)s*2);
  float2 r = *(const float2*)(er + (size_t)d*2);
  float v0 = l.x + r.x, v1 = l.y + r.y;
  v0 = (v0 > 0.f) ? v0 : 0.2f*v0;
  v1 = (v1 > 0.f) ? v1 : 0.2f*v1;
  float2 o = { v0, v1 };
  *(float2*)(escore + (size_t)e*2) = o;
}

// ---------------- softmax + aggregate + bias/relu/head-mean + fused gate + bf16 out ----------------
__global__ __launch_bounds__(256) void k_aggregate(const ushort* __restrict__ hpairh,
    const float* __restrict__ escore, const int* __restrict__ src,
    const int* __restrict__ offs, const int* __restrict__ eidx,
    const float* __restrict__ bias, const float* __restrict__ gwv, const float* __restrict__ gbv,
    float* __restrict__ out, ushort* __restrict__ outh, float* __restrict__ gate, int Nn){
  int n = blockIdx.x*4 + (threadIdx.x >> 6);
  if (n >= Nn) return;
  int lane = threadIdx.x & 63;
  int e0 = offs[n], e1 = offs[n+1];
  float m0 = -3.4e38f, m1 = -3.4e38f;
  for (int i = e0 + lane; i < e1; i += 64){
    int e = eidx[i];
    float2 sc = *(const float2*)(escore + (size_t)e*2);
    m0 = fmaxf(m0, sc.x); m1 = fmaxf(m1, sc.y);
  }
  for (int k = 1; k < 64; k <<= 1){ m0 = fmaxf(m0, __shfl_xor(m0, k)); m1 = fmaxf(m1, __shfl_xor(m1, k)); }
  float s0 = 0.f, s1 = 0.f;
  for (int i = e0 + lane; i < e1; i += 64){
    int e = eidx[i];
    float2 sc = *(const float2*)(escore + (size_t)e*2);
    s0 += expf(sc.x - m0); s1 += expf(sc.y - m1);
  }
  for (int k = 1; k < 64; k <<= 1){ s0 += __shfl_xor(s0, k); s1 += __shfl_xor(s1, k); }

  int half = lane >> 5;
  int sub  = lane & 31;
  int head = sub >> 4;
  float mh  = head ? m1 : m0;
  float invh = head ? (s1 > 0.f ? 1.f/s1 : 0.f) : (s0 > 0.f ? 1.f/s0 : 0.f);

  float acc[8] = {0,0,0,0,0,0,0,0};
  for (int i = e0 + half; i < e1; i += 2){
    int e = eidx[i];
    float w = expf(escore[(size_t)e*2 + head] - mh) * invh;
    uint4 hv = *(const uint4*)(hpairh + (size_t)src[e]*256 + sub*8);
    acc[0] += w * bf_lo(hv.x); acc[1] += w * bf_hi(hv.x);
    acc[2] += w * bf_lo(hv.y); acc[3] += w * bf_hi(hv.y);
    acc[4] += w * bf_lo(hv.z); acc[5] += w * bf_hi(hv.z);
    acc[6] += w * bf_lo(hv.w); acc[7] += w * bf_hi(hv.w);
  }
  #pragma unroll
  for (int k = 0; k < 8; k++) acc[k] += __shfl_xor(acc[k], 32);
  float t[8];
  #pragma unroll
  for (int k = 0; k < 8; k++) t[k] = fmaxf(acc[k] + bias[sub*8 + k], 0.f);
  float o[8];
  #pragma unroll
  for (int k = 0; k < 8; k++) o[k] = 0.5f*(t[k] + __shfl_xor(t[k], 16));
  if (lane < 16){
    float4 v0 = { o[0], o[1], o[2], o[3] };
    float4 v1 = { o[4], o[5], o[6], o[7] };
    *(float4*)(out + (size_t)n*128 + sub*8) = v0;
    *(float4*)(out + (size_t)n*128 + sub*8 + 4) = v1;
    ushort u[8] = { (ushort)f2bf_rne(o[0]), (ushort)f2bf_rne(o[1]), (ushort)f2bf_rne(o[2]), (ushort)f2bf_rne(o[3]),
                    (ushort)f2bf_rne(o[4]), (ushort)f2bf_rne(o[5]), (ushort)f2bf_rne(o[6]), (ushort)f2bf_rne(o[7]) };
    *(uint4*)(outh + (size_t)n*128 + sub*8) = *(uint4*)u;
    float gp = 0.f;
    #pragma unroll
    for (int k = 0; k < 8; k++) gp += o[k]*gwv[sub*8 + k];
    #pragma unroll
    for (int d = 1; d < 16; d <<= 1) gp += __shfl_xor(gp, d);
    if (sub == 0) gate[n] = gp + gbv[0];
  }
}

// ---------------- pool gate (only for layer-0 input) ----------------
__global__ __launch_bounds__(256) void k_gate(const float* __restrict__ x, const float* __restrict__ gw,
    const float* __restrict__ gb, float* __restrict__ gate, int Nn){
  int n = blockIdx.x*4 + (threadIdx.x >> 6);
  if (n >= Nn) return;
  int lane = threadIdx.x & 63;
  float2 xv = *(const float2*)(x + (size_t)n*128 + lane*2);
  float2 gv = *(const float2*)(gw + lane*2);
  float p = xv.x*gv.x + xv.y*gv.y;
  for (int k = 1; k < 64; k <<= 1) p += __shfl_xor(p, k);
  if (lane == 0) gate[n] = p + gb[0];
}

// ---------------- pool stats ----------------
__global__ __launch_bounds__(256) void k_pool_stats(const float* __restrict__ gate,
    const int* __restrict__ gstart, float* __restrict__ pm, float* __restrict__ psinv){
  int b = blockIdx.x;
  int n0 = gstart[b], n1 = gstart[b+1];
  int tid = threadIdx.x, lane = tid & 63, wid = tid >> 6;
  __shared__ float red[4];
  float m = -3.4e38f;
  for (int n = n0 + tid; n < n1; n += 256) m = fmaxf(m, gate[n]);
  for (int k = 1; k < 64; k <<= 1) m = fmaxf(m, __shfl_xor(m, k));
  if (lane == 0) red[wid] = m;
  __syncthreads();
  m = fmaxf(fmaxf(red[0], red[1]), fmaxf(red[2], red[3]));
  __syncthreads();
  float s = 0.f;
  for (int n = n0 + tid; n < n1; n += 256) s += expf(gate[n] - m);
  for (int k = 1; k < 64; k <<= 1) s += __shfl_xor(s, k);
  if (lane == 0) red[wid] = s;
  __syncthreads();
  if (tid == 0){
    s = red[0] + red[1] + red[2] + red[3];
    pm[b] = m;
    psinv[b] = (s > 0.f) ? 1.f/s : 0.f;
  }
}

// ---------------- pool partial + reduce ----------------
#define POOL_P 32
__global__ __launch_bounds__(128) void k_pool_partial(const float* __restrict__ x,
    const float* __restrict__ gate, const int* __restrict__ gstart,
    const float* __restrict__ pm, const float* __restrict__ psinv,
    float* __restrict__ partials){
  int b = blockIdx.x;
  int p = blockIdx.y;
  int n0 = gstart[b], n1 = gstart[b+1];
  int tid = threadIdx.x;
  float m = pm[b], inv = psinv[b];
  float acc = 0.f;
  for (int n = n0 + p; n < n1; n += POOL_P){
    float w = expf(gate[n] - m) * inv;
    acc += w * x[(size_t)n*128 + tid];
  }
  partials[((size_t)b*POOL_P + p)*128 + tid] = acc;
}

__global__ __launch_bounds__(128) void k_pool_reduce(const float* __restrict__ partials,
    float* __restrict__ hg){
  int b = blockIdx.x;
  int tid = threadIdx.x;
  float s = 0.f;
  #pragma unroll
  for (int p = 0; p < POOL_P; p++) s += partials[((size_t)b*POOL_P + p)*128 + tid];
  hg[(size_t)b*128 + tid] = s;
}

// ---------------- fused LSTM (2 layers x 4 steps) + final head, coalesced WT ----------------
// gates[j] = bias2[j] + sum_k xh[k] * WT[k*512+j]  -- lane-consecutive j => coalesced.
__global__ __launch_bounds__(512) void k_lstm_all(const float* __restrict__ seq,
    const float* __restrict__ WT, const float* __restrict__ bias2,
    const float* __restrict__ cw, const float* __restrict__ cb,
    float* __restrict__ out, int B){
  int b = blockIdx.x;
  int j = threadIdx.x;
  __shared__ float xh[256];
  __shared__ float gates[512];
  __shared__ float hcur[128], ccur[128];
  __shared__ float l0out[4][128];
  __shared__ float red[2];

  for (int l = 0; l < 2; l++){
    const float* W = WT + (size_t)l*256*512;
    const float* bi = bias2 + l*512;
    if (j < 128){ hcur[j] = 0.f; ccur[j] = 0.f; }
    __syncthreads();
    for (int t = 0; t < 4; t++){
      if (j < 128) xh[j] = (l == 0) ? seq[(size_t)t*B*128 + (size_t)b*128 + j] : l0out[t][j];
      else if (j < 256) xh[j] = hcur[j - 128];
      __syncthreads();
      float g = bi[j];
      #pragma unroll 8
      for (int k = 0; k < 256; k++) g = fmaf(xh[k], W[(size_t)k*512 + j], g);
      gates[j] = g;
      __syncthreads();
      if (j < 128){
        float gi = sigmoidf_(gates[j]);
        float gf = sigmoidf_(gates[128 + j]);
        float gg = tanhf(gates[256 + j]);
        float go = sigmoidf_(gates[384 + j]);
        float c = gf * ccur[j] + gi * gg;
        float h = go * tanhf(c);
        ccur[j] = c;
        hcur[j] = h;
        if (l == 0) l0out[t][j] = h;
      }
      __syncthreads();
    }
  }
  float p = (j < 128) ? hcur[j] * cw[j] : 0.f;
  if (j < 128){
    for (int k = 1; k < 64; k <<= 1) p += __shfl_xor(p, k);
    if ((j & 63) == 0) red[j >> 6] = p;
  }
  __syncthreads();
  if (j == 0) out[b] = sigmoidf_(red[0] + red[1] + cb[0]);
}

extern "C" void kernel_launch(void* const* d_in, const int* in_sizes, int n_in,
                              void* d_out, int out_size, void* d_ws, size_t ws_size,
                              hipStream_t stream){
  const float* nfeats = (const float*)d_in[0];
  const int*   src    = (const int*)d_in[1];
  const int*   dst    = (const int*)d_in[2];
  const int*   ng     = (const int*)d_in[3];
  const float* Wm[3]  = { (const float*)d_in[4],  (const float*)d_in[8],  (const float*)d_in[12] };
  const float* al[3]  = { (const float*)d_in[5],  (const float*)d_in[9],  (const float*)d_in[13] };
  const float* ar[3]  = { (const float*)d_in[6],  (const float*)d_in[10], (const float*)d_in[14] };
  const float* bb[3]  = { (const float*)d_in[7],  (const float*)d_in[11], (const float*)d_in[15] };
  const float* gw[4]  = { (const float*)d_in[16], (const float*)d_in[18], (const float*)d_in[20], (const float*)d_in[22] };
  const float* gb[4]  = { (const float*)d_in[17], (const float*)d_in[19], (const float*)d_in[21], (const float*)d_in[23] };
  const float* Wih = (const float*)d_in[24];
  const float* Whh = (const float*)d_in[25];
  const float* bih = (const float*)d_in[26];
  const float* bhh = (const float*)d_in[27];
  const float* cw  = (const float*)d_in[28];
  const float* cb  = (const float*)d_in[29];

  const int N = in_sizes[3];      // 50000
  const int E = in_sizes[1];      // 800000
  const int B = out_size;         // 64

  char* p = (char*)d_ws;
  auto alloc = [&](size_t bytes) -> void* {
    void* q = (void*)p;
    p += (bytes + 255) & ~(size_t)255;
    return q;
  };
  ushort* hpairh = (ushort*)alloc((size_t)N*256*2);
  float*  xbuf   = (float*)alloc((size_t)N*128*4);
  ushort* aggh   = (ushort*)alloc((size_t)N*128*2);
  ushort* xh0    = (ushort*)alloc((size_t)N*128*2);
  ushort* Wt     = (ushort*)alloc((size_t)3*256*128*2);
  float*  el     = (float*)alloc((size_t)N*2*4);
  float*  er     = (float*)alloc((size_t)N*2*4);
  float*  escore = (float*)alloc((size_t)E*2*4);
  float*  gate   = (float*)alloc((size_t)N*4);
  int*    deg    = (int*)alloc((size_t)N*4);
  int*    offs   = (int*)alloc((size_t)(N+1)*4);
  int*    cnt    = (int*)alloc((size_t)N*4);
  int*    eidx   = (int*)alloc((size_t)E*4);
  int*    gstart = (int*)alloc((size_t)(B+1)*4);
  int*    csum   = (int*)alloc((size_t)64*4);
  int*    cpre   = (int*)alloc((size_t)64*4);
  float*  seqA   = (float*)alloc((size_t)4*B*128*4);
  float*  pm     = (float*)alloc((size_t)B*4);
  float*  psinv  = (float*)alloc((size_t)B*4);
  float*  partials = (float*)alloc((size_t)B*POOL_P*128*4);
  float*  WT     = (float*)alloc((size_t)2*256*512*4);
  float*  bias2  = (float*)alloc((size_t)2*512*4);

  auto cdiv = [](int a, int b){ return (a + b - 1) / b; };
  const int NB = cdiv(N, CHUNK);   // 49 chunks

  hipMemsetAsync(deg, 0, (size_t)N*4, stream);
  hipMemsetAsync(cnt, 0, (size_t)N*4, stream);
  k_hist<<<cdiv(E,256), 256, 0, stream>>>(dst, deg, E);
  k_chunksum<<<NB, 256, 0, stream>>>(deg, csum, N);
  k_scan_small<<<1, 64, 0, stream>>>(csum, cpre, NB, offs + N);
  k_scan_apply<<<NB, 256, 0, stream>>>(deg, cpre, offs, N);
  k_scatter<<<cdiv(E,256), 256, 0, stream>>>(dst, offs, cnt, eidx, E);
  k_graph_bounds<<<cdiv(N,256), 256, 0, stream>>>(ng, gstart, N, B);

  // conversions
  k_tobf16<<<cdiv(N*16, 256), 256, 0, stream>>>(nfeats, xh0, N*16);   // N*128/8
  for (int l = 0; l < 3; l++)
    k_wt<<<cdiv(256*128, 256), 256, 0, stream>>>(Wm[l], Wt + (size_t)l*256*128, 256*128);
  k_lstm_prep<<<cdiv(2*256*512, 256), 256, 0, stream>>>(Wih, Whh, bih, bhh, WT, bias2);

  auto pool_rest = [&](const float* xv, float* hgv){
    k_pool_stats<<<B, 256, 0, stream>>>(gate, gstart, pm, psinv);
    dim3 pg(B, POOL_P);
    k_pool_partial<<<pg, 128, 0, stream>>>(xv, gate, gstart, pm, psinv, partials);
    k_pool_reduce<<<B, 128, 0, stream>>>(partials, hgv);
  };

  // pool 0 on raw features
  k_gate<<<cdiv(N,4), 256, 0, stream>>>(nfeats, gw[0], gb[0], gate, N);
  pool_rest(nfeats, seqA + 0*(size_t)B*128);

  const ushort* xh = xh0;
  const int strips = cdiv(N, 16);
  for (int layer = 0; layer < 3; layer++){
    k_gemm_mfma<<<cdiv(strips,4), 256, 0, stream>>>(xh, Wt + (size_t)layer*256*128,
        al[layer], ar[layer], hpairh, el, er, N);
    k_edge_scores<<<cdiv(E,256), 256, 0, stream>>>(el, er, src, dst, escore, E);
    k_aggregate<<<cdiv(N,4), 256, 0, stream>>>(hpairh, escore, src, offs, eidx,
        bb[layer], gw[layer+1], gb[layer+1], xbuf, aggh, gate, N);
    pool_rest(xbuf, seqA + (size_t)(layer+1)*B*128);
    xh = aggh;
  }

  k_lstm_all<<<B, 512, 0, stream>>>(seqA, WT, bias2, cw, cb, (float*)d_out, B);
}

// Round 7
// 650.150 us; speedup vs baseline: 2.8619x; 1.0760x over previous
//
#include <hip/hip_runtime.h>
#include <cmath>

// N=50000 nodes, E=800000 edges, B=64 graphs, H=2 heads, D=128, FIN=128, L=2.

typedef __attribute__((ext_vector_type(8))) short short8v;   // 8 x bf16 (4 VGPRs)
typedef __attribute__((ext_vector_type(4))) float float4v;   // MFMA acc

__device__ __forceinline__ float sigmoidf_(float x){ return 1.f/(1.f+expf(-x)); }

__device__ __forceinline__ unsigned f2bf_rne(float f){
  unsigned u = __float_as_uint(f);
  return (u + 0x7fffu + ((u >> 16) & 1u)) >> 16;   // round-nearest-even bf16
}
// fp8 e4m3 (hardware cvt, OCP on gfx950; encode+decode use the same HW format)
__device__ __forceinline__ unsigned char f2fp8(float f){
  unsigned v = __builtin_amdgcn_cvt_pk_fp8_f32(f, f, 0, false);
  return (unsigned char)(v & 0xffu);
}

// ---------------- CSR build (by dst) ----------------
__global__ void k_hist(const int* __restrict__ dst, int* __restrict__ deg, int E){
  int e = blockIdx.x*blockDim.x + threadIdx.x;
  if (e < E) atomicAdd(&deg[dst[e]], 1);
}

// parallel exclusive scan: chunk sums -> tiny scan -> apply
#define CHUNK 1024
__global__ __launch_bounds__(256) void k_chunksum(const int* __restrict__ in, int* __restrict__ csum, int n){
  int b = blockIdx.x;
  int tid = threadIdx.x;
  int v = 0;
  #pragma unroll
  for (int k = 0; k < 4; k++){
    int i = b*CHUNK + tid + k*256;
    if (i < n) v += in[i];
  }
  for (int d = 1; d < 64; d <<= 1) v += __shfl_xor(v, d);
  __shared__ int ws[4];
  if ((tid & 63) == 0) ws[tid>>6] = v;
  __syncthreads();
  if (tid == 0) csum[b] = ws[0]+ws[1]+ws[2]+ws[3];
}

__global__ void k_scan_small(const int* __restrict__ csum, int* __restrict__ cpre, int nb,
                             int* __restrict__ total_out){
  int lane = threadIdx.x;  // 64 threads, nb <= 64
  int v = (lane < nb) ? csum[lane] : 0;
  int incl = v;
  for (int d = 1; d < 64; d <<= 1){ int t = __shfl_up(incl, d); if (lane >= d) incl += t; }
  if (lane < nb) cpre[lane] = incl - v;
  if (lane == 63) *total_out = incl;
}

__global__ __launch_bounds__(256) void k_scan_apply(const int* __restrict__ in, const int* __restrict__ cpre,
                                                    int* __restrict__ offs, int n){
  int b = blockIdx.x;
  int tid = threadIdx.x, lane = tid & 63, wid = tid >> 6;
  int x[4];
  int s = 0;
  #pragma unroll
  for (int k = 0; k < 4; k++){
    int i = b*CHUNK + tid*4 + k;
    x[k] = (i < n) ? in[i] : 0;
    s += x[k];
  }
  int incl = s;
  for (int d = 1; d < 64; d <<= 1){ int t = __shfl_up(incl, d); if (lane >= d) incl += t; }
  __shared__ int ws[4];
  if (lane == 63) ws[wid] = incl;
  __syncthreads();
  int wpre = 0;
  for (int w = 0; w < wid; w++) wpre += ws[w];
  int base = cpre[b] + wpre + incl - s;
  #pragma unroll
  for (int k = 0; k < 4; k++){
    int i = b*CHUNK + tid*4 + k;
    if (i < n) offs[i] = base;
    base += x[k];
  }
}

__global__ void k_graph_bounds(const int* __restrict__ ng, int* __restrict__ gstart, int n, int nb){
  int i = blockIdx.x*blockDim.x + threadIdx.x;
  if (i >= n) return;
  int g = ng[i];
  int gp = (i == 0) ? -1 : ng[i-1];
  for (int b = gp+1; b <= g; b++) gstart[b] = i;
  if (i == n-1) for (int b = g+1; b <= nb; b++) gstart[b] = n;
}

// ---------------- conversions ----------------
__global__ void k_tobf16(const float* __restrict__ in, ushort* __restrict__ out, int n8){
  int i = blockIdx.x*blockDim.x + threadIdx.x;
  if (i >= n8) return;
  float4 a = *(const float4*)(in + (size_t)i*8);
  float4 b = *(const float4*)(in + (size_t)i*8 + 4);
  ushort u[8] = { (ushort)f2bf_rne(a.x), (ushort)f2bf_rne(a.y), (ushort)f2bf_rne(a.z), (ushort)f2bf_rne(a.w),
                  (ushort)f2bf_rne(b.x), (ushort)f2bf_rne(b.y), (ushort)f2bf_rne(b.z), (ushort)f2bf_rne(b.w) };
  *(uint4*)(out + (size_t)i*8) = *(uint4*)u;
}

// W [128,256] f32 -> Wt [256,128] bf16
__global__ void k_wt(const float* __restrict__ W, ushort* __restrict__ Wt, int total){
  int idx = blockIdx.x*blockDim.x + threadIdx.x;
  if (idx >= total) return;
  int c = idx >> 7;
  int k = idx & 127;
  Wt[idx] = (ushort)f2bf_rne(W[(size_t)k*256 + c]);
}

// LSTM weight prep: WT[l][k][j] (k=0..255: x then h; j gate) + combined bias
__global__ void k_lstm_prep(const float* __restrict__ Wih, const float* __restrict__ Whh,
                            const float* __restrict__ bih, const float* __restrict__ bhh,
                            float* __restrict__ WT, float* __restrict__ bias2){
  int idx = blockIdx.x*blockDim.x + threadIdx.x;   // 2*256*512
  if (idx >= 2*256*512) return;
  int l = idx >> 17;
  int r = idx & 131071;
  int k = r >> 9;
  int j = r & 511;
  float v = (k < 128) ? Wih[(size_t)l*512*128 + (size_t)j*128 + k]
                      : Whh[(size_t)l*512*128 + (size_t)j*128 + (k-128)];
  WT[idx] = v;
  if (k == 0) bias2[l*512 + j] = bih[l*512 + j] + bhh[l*512 + j];
}

// ---------------- MFMA GEMM: Y8[M,256](fp8) = Xh[M,128] @ W, fused el/er ----------------
// wave per 16-row strip, all 256 cols. A row=lane&15,k=(lane>>4)*8+j; B col=lane&15 (from Wt);
// C/D col=lane&15, row=(lane>>4)*4+reg  [guide m89-verified].
__global__ __launch_bounds__(256) void k_gemm_mfma(const ushort* __restrict__ Xh,
    const ushort* __restrict__ Wt, const float* __restrict__ alv, const float* __restrict__ arv,
    unsigned char* __restrict__ Y8, float* __restrict__ el, float* __restrict__ er, int M){
  int wave = threadIdx.x >> 6;
  int lane = threadIdx.x & 63;
  int strip = blockIdx.x*4 + wave;
  if (strip*16 >= M) return;
  int m0 = strip*16;
  int l15 = lane & 15;
  int kg  = lane >> 4;
  int arow = m0 + l15; if (arow >= M) arow = M-1;
  short8v a[4];
  const ushort* xrow = Xh + (size_t)arow*128 + kg*8;
  #pragma unroll
  for (int ks = 0; ks < 4; ks++) a[ks] = *(const short8v*)(xrow + ks*32);
  float4v acc[16];
  #pragma unroll
  for (int nt = 0; nt < 16; nt++) acc[nt] = (float4v){0.f,0.f,0.f,0.f};
  #pragma unroll
  for (int nt = 0; nt < 16; nt++){
    const ushort* wrow = Wt + (size_t)(nt*16 + l15)*128 + kg*8;
    #pragma unroll
    for (int ks = 0; ks < 4; ks++){
      short8v b = *(const short8v*)(wrow + ks*32);
      acc[nt] = __builtin_amdgcn_mfma_f32_16x16x32_bf16(a[ks], b, acc[nt], 0, 0, 0);
    }
  }
  float pel0[4]={0,0,0,0}, pel1[4]={0,0,0,0}, per0[4]={0,0,0,0}, per1[4]={0,0,0,0};
  #pragma unroll
  for (int nt = 0; nt < 16; nt++){
    int col = nt*16 + l15;
    float av = alv[col], rv = arv[col];
    #pragma unroll
    for (int j = 0; j < 4; j++){
      float v = acc[nt][j];
      int r = m0 + kg*4 + j;
      if (r < M) Y8[(size_t)r*256 + col] = f2fp8(v);
      if (nt < 8){ pel0[j] += v*av; per0[j] += v*rv; }
      else       { pel1[j] += v*av; per1[j] += v*rv; }
    }
  }
  #pragma unroll
  for (int j = 0; j < 4; j++){
    #pragma unroll
    for (int d = 1; d < 16; d <<= 1){
      pel0[j] += __shfl_xor(pel0[j], d);
      pel1[j] += __shfl_xor(pel1[j], d);
      per0[j] += __shfl_xor(per0[j], d);
      per1[j] += __shfl_xor(per1[j], d);
    }
  }
  if (l15 == 0){
    #pragma unroll
    for (int j = 0; j < 4; j++){
      int r = m0 + kg*4 + j;
      if (r < M){
        el[(size_t)r*2+0] = pel0[j];
        el[(size_t)r*2+1] = pel1[j];
        er[(size_t)r*2+0] = per0[j];
        er[(size_t)r*2+1] = per1[j];
      }
    }
  }
}

// ---------------- fused edge scores + CSR scatter: srcP/escoreP in slot order ----------------
__global__ void k_edge_scatter(const float* __restrict__ el, const float* __restrict__ er,
    const int* __restrict__ src, const int* __restrict__ dst,
    const int* __restrict__ offs, int* __restrict__ cnt,
    int* __restrict__ srcP, float2* __restrict__ escoreP, int E){
  int e = blockIdx.x*blockDim.x + threadIdx.x;
  if (e >= E) return;
  int s = src[e], d = dst[e];
  float2 l = *(const float2*)(el + (size_t)s*2);
  float2 r = *(const float2*)(er + (size_t)d*2);
  float v0 = l.x + r.x, v1 = l.y + r.y;
  v0 = (v0 > 0.f) ? v0 : 0.2f*v0;
  v1 = (v1 > 0.f) ? v1 : 0.2f*v1;
  int p = atomicAdd(&cnt[d], 1);
  int slot = offs[d] + p;
  srcP[slot] = s;
  float2 o = { v0, v1 };
  escoreP[slot] = o;
}

// ---------------- softmax + aggregate (fp8 gather) + bias/relu/head-mean + gate + bf16 out ----------------
__global__ __launch_bounds__(256) void k_aggregate(const unsigned char* __restrict__ hpair8,
    const float* __restrict__ escoreP, const int* __restrict__ srcP,
    const int* __restrict__ offs,
    const float* __restrict__ bias, const float* __restrict__ gwv, const float* __restrict__ gbv,
    float* __restrict__ out, ushort* __restrict__ outh, float* __restrict__ gate, int Nn){
  int n = blockIdx.x*4 + (threadIdx.x >> 6);
  if (n >= Nn) return;
  int lane = threadIdx.x & 63;
  int e0 = offs[n], e1 = offs[n+1];
  float m0 = -3.4e38f, m1 = -3.4e38f;
  for (int i = e0 + lane; i < e1; i += 64){
    float2 sc = *(const float2*)(escoreP + (size_t)i*2);
    m0 = fmaxf(m0, sc.x); m1 = fmaxf(m1, sc.y);
  }
  for (int k = 1; k < 64; k <<= 1){ m0 = fmaxf(m0, __shfl_xor(m0, k)); m1 = fmaxf(m1, __shfl_xor(m1, k)); }
  float s0 = 0.f, s1 = 0.f;
  for (int i = e0 + lane; i < e1; i += 64){
    float2 sc = *(const float2*)(escoreP + (size_t)i*2);
    s0 += expf(sc.x - m0); s1 += expf(sc.y - m1);
  }
  for (int k = 1; k < 64; k <<= 1){ s0 += __shfl_xor(s0, k); s1 += __shfl_xor(s1, k); }

  int half = lane >> 5;        // which edge of the pair
  int sub  = lane & 31;        // 8-dim slice of flat 256
  int head = sub >> 4;
  float mh  = head ? m1 : m0;
  float invh = head ? (s1 > 0.f ? 1.f/s1 : 0.f) : (s0 > 0.f ? 1.f/s0 : 0.f);

  float acc[8] = {0,0,0,0,0,0,0,0};
  for (int i = e0 + half; i < e1; i += 2){
    int s = srcP[i];                                   // wave-broadcast
    float sc = escoreP[(size_t)i*2 + head];            // 2 distinct dwords/wave
    float w = expf(sc - mh) * invh;
    uint2 hv = *(const uint2*)(hpair8 + (size_t)s*256 + sub*8);
    acc[0] += w * __builtin_amdgcn_cvt_f32_fp8(hv.x, 0);
    acc[1] += w * __builtin_amdgcn_cvt_f32_fp8(hv.x, 1);
    acc[2] += w * __builtin_amdgcn_cvt_f32_fp8(hv.x, 2);
    acc[3] += w * __builtin_amdgcn_cvt_f32_fp8(hv.x, 3);
    acc[4] += w * __builtin_amdgcn_cvt_f32_fp8(hv.y, 0);
    acc[5] += w * __builtin_amdgcn_cvt_f32_fp8(hv.y, 1);
    acc[6] += w * __builtin_amdgcn_cvt_f32_fp8(hv.y, 2);
    acc[7] += w * __builtin_amdgcn_cvt_f32_fp8(hv.y, 3);
  }
  #pragma unroll
  for (int k = 0; k < 8; k++) acc[k] += __shfl_xor(acc[k], 32);
  float t[8];
  #pragma unroll
  for (int k = 0; k < 8; k++) t[k] = fmaxf(acc[k] + bias[sub*8 + k], 0.f);
  float o[8];
  #pragma unroll
  for (int k = 0; k < 8; k++) o[k] = 0.5f*(t[k] + __shfl_xor(t[k], 16));
  if (lane < 16){
    float4 v0 = { o[0], o[1], o[2], o[3] };
    float4 v1 = { o[4], o[5], o[6], o[7] };
    *(float4*)(out + (size_t)n*128 + sub*8) = v0;
    *(float4*)(out + (size_t)n*128 + sub*8 + 4) = v1;
    ushort u[8] = { (ushort)f2bf_rne(o[0]), (ushort)f2bf_rne(o[1]), (ushort)f2bf_rne(o[2]), (ushort)f2bf_rne(o[3]),
                    (ushort)f2bf_rne(o[4]), (ushort)f2bf_rne(o[5]), (ushort)f2bf_rne(o[6]), (ushort)f2bf_rne(o[7]) };
    *(uint4*)(outh + (size_t)n*128 + sub*8) = *(uint4*)u;
    float gp = 0.f;
    #pragma unroll
    for (int k = 0; k < 8; k++) gp += o[k]*gwv[sub*8 + k];
    #pragma unroll
    for (int d = 1; d < 16; d <<= 1) gp += __shfl_xor(gp, d);
    if (sub == 0) gate[n] = gp + gbv[0];
  }
}

// ---------------- pool gate (only for layer-0 input) ----------------
__global__ __launch_bounds__(256) void k_gate(const float* __restrict__ x, const float* __restrict__ gw,
    const float* __restrict__ gb, float* __restrict__ gate, int Nn){
  int n = blockIdx.x*4 + (threadIdx.x >> 6);
  if (n >= Nn) return;
  int lane = threadIdx.x & 63;
  float2 xv = *(const float2*)(x + (size_t)n*128 + lane*2);
  float2 gv = *(const float2*)(gw + lane*2);
  float p = xv.x*gv.x + xv.y*gv.y;
  for (int k = 1; k < 64; k <<= 1) p += __shfl_xor(p, k);
  if (lane == 0) gate[n] = p + gb[0];
}

// ---------------- pool stats ----------------
__global__ __launch_bounds__(256) void k_pool_stats(const float* __restrict__ gate,
    const int* __restrict__ gstart, float* __restrict__ pm, float* __restrict__ psinv){
  int b = blockIdx.x;
  int n0 = gstart[b], n1 = gstart[b+1];
  int tid = threadIdx.x, lane = tid & 63, wid = tid >> 6;
  __shared__ float red[4];
  float m = -3.4e38f;
  for (int n = n0 + tid; n < n1; n += 256) m = fmaxf(m, gate[n]);
  for (int k = 1; k < 64; k <<= 1) m = fmaxf(m, __shfl_xor(m, k));
  if (lane == 0) red[wid] = m;
  __syncthreads();
  m = fmaxf(fmaxf(red[0], red[1]), fmaxf(red[2], red[3]));
  __syncthreads();
  float s = 0.f;
  for (int n = n0 + tid; n < n1; n += 256) s += expf(gate[n] - m);
  for (int k = 1; k < 64; k <<= 1) s += __shfl_xor(s, k);
  if (lane == 0) red[wid] = s;
  __syncthreads();
  if (tid == 0){
    s = red[0] + red[1] + red[2] + red[3];
    pm[b] = m;
    psinv[b] = (s > 0.f) ? 1.f/s : 0.f;
  }
}

// ---------------- pool partial + reduce ----------------
#define POOL_P 32
__global__ __launch_bounds__(128) void k_pool_partial(const float* __restrict__ x,
    const float* __restrict__ gate, const int* __restrict__ gstart,
    const float* __restrict__ pm, const float* __restrict__ psinv,
    float* __restrict__ partials){
  int b = blockIdx.x;
  int p = blockIdx.y;
  int n0 = gstart[b], n1 = gstart[b+1];
  int tid = threadIdx.x;
  float m = pm[b], inv = psinv[b];
  float acc = 0.f;
  for (int n = n0 + p; n < n1; n += POOL_P){
    float w = expf(gate[n] - m) * inv;
    acc += w * x[(size_t)n*128 + tid];
  }
  partials[((size_t)b*POOL_P + p)*128 + tid] = acc;
}

__global__ __launch_bounds__(128) void k_pool_reduce(const float* __restrict__ partials,
    float* __restrict__ hg){
  int b = blockIdx.x;
  int tid = threadIdx.x;
  float s = 0.f;
  #pragma unroll
  for (int p = 0; p < POOL_P; p++) s += partials[((size_t)b*POOL_P + p)*128 + tid];
  hg[(size_t)b*128 + tid] = s;
}

// ---------------- fused LSTM (2 layers x 4 steps) + final head, coalesced WT ----------------
__global__ __launch_bounds__(512) void k_lstm_all(const float* __restrict__ seq,
    const float* __restrict__ WT, const float* __restrict__ bias2,
    const float* __restrict__ cw, const float* __restrict__ cb,
    float* __restrict__ out, int B){
  int b = blockIdx.x;
  int j = threadIdx.x;
  __shared__ float xh[256];
  __shared__ float gates[512];
  __shared__ float hcur[128], ccur[128];
  __shared__ float l0out[4][128];
  __shared__ float red[2];

  for (int l = 0; l < 2; l++){
    const float* W = WT + (size_t)l*256*512;
    const float* bi = bias2 + l*512;
    if (j < 128){ hcur[j] = 0.f; ccur[j] = 0.f; }
    __syncthreads();
    for (int t = 0; t < 4; t++){
      if (j < 128) xh[j] = (l == 0) ? seq[(size_t)t*B*128 + (size_t)b*128 + j] : l0out[t][j];
      else if (j < 256) xh[j] = hcur[j - 128];
      __syncthreads();
      float g = bi[j];
      #pragma unroll 8
      for (int k = 0; k < 256; k++) g = fmaf(xh[k], W[(size_t)k*512 + j], g);
      gates[j] = g;
      __syncthreads();
      if (j < 128){
        float gi = sigmoidf_(gates[j]);
        float gf = sigmoidf_(gates[128 + j]);
        float gg = tanhf(gates[256 + j]);
        float go = sigmoidf_(gates[384 + j]);
        float c = gf * ccur[j] + gi * gg;
        float h = go * tanhf(c);
        ccur[j] = c;
        hcur[j] = h;
        if (l == 0) l0out[t][j] = h;
      }
      __syncthreads();
    }
  }
  float p = (j < 128) ? hcur[j] * cw[j] : 0.f;
  if (j < 128){
    for (int k = 1; k < 64; k <<= 1) p += __shfl_xor(p, k);
    if ((j & 63) == 0) red[j >> 6] = p;
  }
  __syncthreads();
  if (j == 0) out[b] = sigmoidf_(red[0] + red[1] + cb[0]);
}

extern "C" void kernel_launch(void* const* d_in, const int* in_sizes, int n_in,
                              void* d_out, int out_size, void* d_ws, size_t ws_size,
                              hipStream_t stream){
  const float* nfeats = (const float*)d_in[0];
  const int*   src    = (const int*)d_in[1];
  const int*   dst    = (const int*)d_in[2];
  const int*   ng     = (const int*)d_in[3];
  const float* Wm[3]  = { (const float*)d_in[4],  (const float*)d_in[8],  (const float*)d_in[12] };
  const float* al[3]  = { (const float*)d_in[5],  (const float*)d_in[9],  (const float*)d_in[13] };
  const float* ar[3]  = { (const float*)d_in[6],  (const float*)d_in[10], (const float*)d_in[14] };
  const float* bb[3]  = { (const float*)d_in[7],  (const float*)d_in[11], (const float*)d_in[15] };
  const float* gw[4]  = { (const float*)d_in[16], (const float*)d_in[18], (const float*)d_in[20], (const float*)d_in[22] };
  const float* gb[4]  = { (const float*)d_in[17], (const float*)d_in[19], (const float*)d_in[21], (const float*)d_in[23] };
  const float* Wih = (const float*)d_in[24];
  const float* Whh = (const float*)d_in[25];
  const float* bih = (const float*)d_in[26];
  const float* bhh = (const float*)d_in[27];
  const float* cw  = (const float*)d_in[28];
  const float* cb  = (const float*)d_in[29];

  const int N = in_sizes[3];      // 50000
  const int E = in_sizes[1];      // 800000
  const int B = out_size;         // 64

  char* p = (char*)d_ws;
  auto alloc = [&](size_t bytes) -> void* {
    void* q = (void*)p;
    p += (bytes + 255) & ~(size_t)255;
    return q;
  };
  unsigned char* hpair8 = (unsigned char*)alloc((size_t)N*256);
  float*  xbuf   = (float*)alloc((size_t)N*128*4);
  ushort* aggh   = (ushort*)alloc((size_t)N*128*2);
  ushort* xh0    = (ushort*)alloc((size_t)N*128*2);
  ushort* Wt     = (ushort*)alloc((size_t)3*256*128*2);
  float*  el     = (float*)alloc((size_t)N*2*4);
  float*  er     = (float*)alloc((size_t)N*2*4);
  float*  escoreP= (float*)alloc((size_t)E*2*4);
  int*    srcP   = (int*)alloc((size_t)E*4);
  float*  gate   = (float*)alloc((size_t)N*4);
  int*    deg    = (int*)alloc((size_t)N*4);
  int*    offs   = (int*)alloc((size_t)(N+1)*4);
  int*    cnt    = (int*)alloc((size_t)N*4);
  int*    gstart = (int*)alloc((size_t)(B+1)*4);
  int*    csum   = (int*)alloc((size_t)64*4);
  int*    cpre   = (int*)alloc((size_t)64*4);
  float*  seqA   = (float*)alloc((size_t)4*B*128*4);
  float*  pm     = (float*)alloc((size_t)B*4);
  float*  psinv  = (float*)alloc((size_t)B*4);
  float*  partials = (float*)alloc((size_t)B*POOL_P*128*4);
  float*  WT     = (float*)alloc((size_t)2*256*512*4);
  float*  bias2  = (float*)alloc((size_t)2*512*4);

  auto cdiv = [](int a, int b){ return (a + b - 1) / b; };
  const int NB = cdiv(N, CHUNK);   // 49 chunks

  hipMemsetAsync(deg, 0, (size_t)N*4, stream);
  k_hist<<<cdiv(E,256), 256, 0, stream>>>(dst, deg, E);
  k_chunksum<<<NB, 256, 0, stream>>>(deg, csum, N);
  k_scan_small<<<1, 64, 0, stream>>>(csum, cpre, NB, offs + N);
  k_scan_apply<<<NB, 256, 0, stream>>>(deg, cpre, offs, N);
  k_graph_bounds<<<cdiv(N,256), 256, 0, stream>>>(ng, gstart, N, B);

  // conversions
  k_tobf16<<<cdiv(N*16, 256), 256, 0, stream>>>(nfeats, xh0, N*16);   // N*128/8
  for (int l = 0; l < 3; l++)
    k_wt<<<cdiv(256*128, 256), 256, 0, stream>>>(Wm[l], Wt + (size_t)l*256*128, 256*128);
  k_lstm_prep<<<cdiv(2*256*512, 256), 256, 0, stream>>>(Wih, Whh, bih, bhh, WT, bias2);

  auto pool_rest = [&](const float* xv, float* hgv){
    k_pool_stats<<<B, 256, 0, stream>>>(gate, gstart, pm, psinv);
    dim3 pg(B, POOL_P);
    k_pool_partial<<<pg, 128, 0, stream>>>(xv, gate, gstart, pm, psinv, partials);
    k_pool_reduce<<<B, 128, 0, stream>>>(partials, hgv);
  };

  // pool 0 on raw features
  k_gate<<<cdiv(N,4), 256, 0, stream>>>(nfeats, gw[0], gb[0], gate, N);
  pool_rest(nfeats, seqA + 0*(size_t)B*128);

  const ushort* xh = xh0;
  const int strips = cdiv(N, 16);
  for (int layer = 0; layer < 3; layer++){
    k_gemm_mfma<<<cdiv(strips,4), 256, 0, stream>>>(xh, Wt + (size_t)layer*256*128,
        al[layer], ar[layer], hpair8, el, er, N);
    hipMemsetAsync(cnt, 0, (size_t)N*4, stream);
    k_edge_scatter<<<cdiv(E,256), 256, 0, stream>>>(el, er, src, dst, offs, cnt,
        srcP, (float2*)escoreP, E);
    k_aggregate<<<cdiv(N,4), 256, 0, stream>>>(hpair8, escoreP, srcP, offs,
        bb[layer], gw[layer+1], gb[layer+1], xbuf, aggh, gate, N);
    pool_rest(xbuf, seqA + (size_t)(layer+1)*B*128);
    xh = aggh;
  }

  k_lstm_all<<<B, 512, 0, stream>>>(seqA, WT, bias2, cw, cb, (float*)d_out, B);
}